// Round 1
// baseline (924.134 us; speedup 1.0000x reference)
//
#include <hip/hip_runtime.h>
#include <hip/hip_bf16.h>

// GCN 3-layer forward for MI355X (gfx950).
// Pipeline per launch (deterministic up to atomic fp-sum order, within tol):
//   1. histogram in-degree over dst          (atomicAdd int)
//   2. exclusive scan -> CSR rowptr          (single 1024-thread block)
//   3. dinv[i] = rsqrt(deg_i + 1)            (self-loop included)
//   4. scatter edges into CSR (src, w=dinv[s]*dinv[d])
//   5. per layer: f32 register-tiled GEMM h=X@W, then wave-per-node
//      CSR gather-reduce with fused +bias, +self-loop, ReLU.

constexpr int N_NODES = 100000;
constexpr int E_EDGES = 1600000;

__global__ __launch_bounds__(256) void count_kernel(
    const int* __restrict__ dst, int* __restrict__ cnt) {
  int e = blockIdx.x * 256 + threadIdx.x;
  if (e < E_EDGES) atomicAdd(&cnt[dst[e]], 1);
}

__global__ __launch_bounds__(1024) void scan_kernel(
    const int* __restrict__ cnt, int* __restrict__ rowptr) {
  __shared__ int part[1024];
  const int t = threadIdx.x;
  constexpr int CH = (N_NODES + 1023) / 1024;  // 98
  int b = t * CH;
  int e = min(b + CH, N_NODES);
  int s = 0;
  for (int i = b; i < e; ++i) s += cnt[i];
  part[t] = s;
  __syncthreads();
  for (int off = 1; off < 1024; off <<= 1) {
    int add = (t >= off) ? part[t - off] : 0;
    __syncthreads();
    part[t] += add;
    __syncthreads();
  }
  int run = part[t] - s;  // exclusive prefix of this chunk
  for (int i = b; i < e; ++i) { rowptr[i] = run; run += cnt[i]; }
  if (t == 1023) rowptr[N_NODES] = part[1023];
}

__global__ __launch_bounds__(256) void dinv_kernel(
    const int* __restrict__ cnt, float* __restrict__ dinv) {
  int i = blockIdx.x * 256 + threadIdx.x;
  if (i < N_NODES) dinv[i] = rsqrtf((float)cnt[i] + 1.0f);  // +1 self loop
}

__global__ __launch_bounds__(256) void scatter_kernel(
    const int* __restrict__ src, const int* __restrict__ dst,
    const int* __restrict__ rowptr, int* __restrict__ cursor,
    const float* __restrict__ dinv, int* __restrict__ eSrc,
    float* __restrict__ eW) {
  int e = blockIdx.x * 256 + threadIdx.x;
  if (e < E_EDGES) {
    int s = src[e], d = dst[e];
    int pos = rowptr[d] + atomicAdd(&cursor[d], 1);
    eSrc[pos] = s;
    eW[pos] = dinv[s] * dinv[d];
  }
}

// f32 GEMM: H[N, OC] = X[N, 128] @ W[128, OC]. Block tile 128 x OC,
// 16x16 thread grid, micro-tile 8 x (OC/16), K staged in LDS chunks of 32.
template <int OC>
__global__ __launch_bounds__(256) void gemm_kernel(
    const float* __restrict__ X, const float* __restrict__ W,
    float* __restrict__ H) {
  constexpr int K = 128;
  constexpr int KC = 32;
  constexpr int MC = OC / 16;  // cols per thread: 8 (OC=128) or 4 (OC=64)
  __shared__ float xs[KC][128 + 4];
  __shared__ float ws[KC][OC + 4];
  const int t = threadIdx.x;
  const int tx = t & 15, ty = t >> 4;
  const int row0 = blockIdx.x * 128;

  float acc[8][MC];
#pragma unroll
  for (int i = 0; i < 8; ++i)
#pragma unroll
    for (int j = 0; j < MC; ++j) acc[i][j] = 0.f;

  for (int kc = 0; kc < K; kc += KC) {
    __syncthreads();
    // X tile: 128 rows x KC -> xs[k][row] (transposed store)
    const float4* Xv = (const float4*)X;
#pragma unroll
    for (int it = 0; it < 4; ++it) {
      int idx = it * 256 + t;      // 0..1023
      int r = idx >> 3;            // KC/4 = 8 float4 per row
      int q = idx & 7;
      int gr = row0 + r;
      float4 v = make_float4(0.f, 0.f, 0.f, 0.f);
      if (gr < N_NODES) v = Xv[(size_t)gr * (K / 4) + (kc >> 2) + q];
      xs[q * 4 + 0][r] = v.x;
      xs[q * 4 + 1][r] = v.y;
      xs[q * 4 + 2][r] = v.z;
      xs[q * 4 + 3][r] = v.w;
    }
    // W tile: KC x OC -> ws[k][c] (direct, coalesced)
    const float4* Wv = (const float4*)W;
    constexpr int NW = KC * OC / 4 / 256;  // 4 or 2
#pragma unroll
    for (int it = 0; it < NW; ++it) {
      int idx = it * 256 + t;
      int kr = idx / (OC / 4);
      int cq = idx % (OC / 4);
      float4 v = Wv[(size_t)(kc + kr) * (OC / 4) + cq];
      *(float4*)&ws[kr][cq * 4] = v;
    }
    __syncthreads();
#pragma unroll
    for (int k = 0; k < KC; ++k) {
      float xr[8];
#pragma unroll
      for (int i = 0; i < 8; ++i) xr[i] = xs[k][ty * 8 + i];
      float wc[MC];
#pragma unroll
      for (int j = 0; j < MC; ++j) wc[j] = ws[k][tx * MC + j];
#pragma unroll
      for (int i = 0; i < 8; ++i)
#pragma unroll
        for (int j = 0; j < MC; ++j)
          acc[i][j] = fmaf(xr[i], wc[j], acc[i][j]);
    }
  }
#pragma unroll
  for (int i = 0; i < 8; ++i) {
    int gr = row0 + ty * 8 + i;
    if (gr < N_NODES) {
#pragma unroll
      for (int j = 0; j < MC; j += 4) {
        float4 v =
            make_float4(acc[i][j], acc[i][j + 1], acc[i][j + 2], acc[i][j + 3]);
        *(float4*)&H[(size_t)gr * OC + tx * MC + j] = v;
      }
    }
  }
}

// Wave-per-node CSR aggregation: Y[n] = relu(b + dinv[n]^2*H[n] +
// sum_e w_e * H[src_e]).  OC=128 -> float2/lane, OC=64 -> float/lane.
template <int OC>
__global__ __launch_bounds__(256) void agg_kernel(
    const float* __restrict__ H, const int* __restrict__ rowptr,
    const int* __restrict__ eSrc, const float* __restrict__ eW,
    const float* __restrict__ dinv, const float* __restrict__ bias,
    float* __restrict__ Y) {
  const int wave = threadIdx.x >> 6;
  const int lane = threadIdx.x & 63;
  const int n = blockIdx.x * 4 + wave;
  if (n >= N_NODES) return;
  const float dn = dinv[n];
  const float selfw = dn * dn;
  const int beg = rowptr[n], end = rowptr[n + 1];

  if constexpr (OC == 128) {
    const float2* H2 = (const float2*)H;
    float2 hv = H2[(size_t)n * 64 + lane];
    float ax = hv.x * selfw, ay = hv.y * selfw;
    for (int j = beg; j < end; ++j) {
      int s = eSrc[j];
      float w = eW[j];
      float2 v = H2[(size_t)s * 64 + lane];
      ax = fmaf(v.x, w, ax);
      ay = fmaf(v.y, w, ay);
    }
    float2 bb = ((const float2*)bias)[lane];
    float2 o;
    o.x = fmaxf(ax + bb.x, 0.f);
    o.y = fmaxf(ay + bb.y, 0.f);
    ((float2*)Y)[(size_t)n * 64 + lane] = o;
  } else {
    float a = H[(size_t)n * 64 + lane] * selfw;
    for (int j = beg; j < end; ++j) {
      int s = eSrc[j];
      float w = eW[j];
      a = fmaf(H[(size_t)s * 64 + lane], w, a);
    }
    Y[(size_t)n * 64 + lane] = fmaxf(a + bias[lane], 0.f);
  }
}

extern "C" void kernel_launch(void* const* d_in, const int* in_sizes, int n_in,
                              void* d_out, int out_size, void* d_ws,
                              size_t ws_size, hipStream_t stream) {
  const float* x = (const float*)d_in[0];
  const int* ei = (const int*)d_in[1];
  const float* W1 = (const float*)d_in[2];
  const float* b1 = (const float*)d_in[3];
  const float* W2 = (const float*)d_in[4];
  const float* b2 = (const float*)d_in[5];
  const float* W3 = (const float*)d_in[6];
  const float* b3 = (const float*)d_in[7];
  const int* src = ei;
  const int* dst = ei + E_EDGES;

  size_t off = 0;
  auto alloc = [&](size_t bytes) -> void* {
    void* p = (char*)d_ws + off;
    off += (bytes + 255) & ~(size_t)255;
    return p;
  };
  int* cnt = (int*)alloc((size_t)N_NODES * 4);
  int* rowptr = (int*)alloc((size_t)(N_NODES + 1) * 4);
  int* cursor = (int*)alloc((size_t)N_NODES * 4);
  float* dinv = (float*)alloc((size_t)N_NODES * 4);
  int* eSrc = (int*)alloc((size_t)E_EDGES * 4);
  float* eW = (float*)alloc((size_t)E_EDGES * 4);
  float* h = (float*)alloc((size_t)N_NODES * 128 * 4);
  float* A = (float*)alloc((size_t)N_NODES * 128 * 4);

  hipMemsetAsync(cnt, 0, (size_t)N_NODES * 4, stream);
  hipMemsetAsync(cursor, 0, (size_t)N_NODES * 4, stream);

  const int EB = (E_EDGES + 255) / 256;
  const int NB = (N_NODES + 255) / 256;
  count_kernel<<<EB, 256, 0, stream>>>(dst, cnt);
  scan_kernel<<<1, 1024, 0, stream>>>(cnt, rowptr);
  dinv_kernel<<<NB, 256, 0, stream>>>(cnt, dinv);
  scatter_kernel<<<EB, 256, 0, stream>>>(src, dst, rowptr, cursor, dinv, eSrc,
                                         eW);

  const int GB = (N_NODES + 127) / 128;  // 782
  const int AB = (N_NODES + 3) / 4;      // 25000

  gemm_kernel<128><<<GB, 256, 0, stream>>>(x, W1, h);
  agg_kernel<128><<<AB, 256, 0, stream>>>(h, rowptr, eSrc, eW, dinv, b1, A);
  gemm_kernel<128><<<GB, 256, 0, stream>>>(A, W2, h);
  agg_kernel<128><<<AB, 256, 0, stream>>>(h, rowptr, eSrc, eW, dinv, b2, A);
  gemm_kernel<64><<<GB, 256, 0, stream>>>(A, W3, h);
  agg_kernel<64><<<AB, 256, 0, stream>>>(h, rowptr, eSrc, eW, dinv, b3,
                                         (float*)d_out);
}

// Round 2
// 764.565 us; speedup vs baseline: 1.2087x; 1.2087x over previous
//
#include <hip/hip_runtime.h>
#include <hip/hip_bf16.h>

// GCN 3-layer forward for MI355X (gfx950).
// Pipeline per launch (deterministic up to atomic fp-sum order, within tol):
//   1. histogram in-degree over dst          (atomicAdd int)
//   2. exclusive scan -> CSR rowptr          (single 1024-thread block)
//   3. dinv[i] = rsqrt(deg_i + 1)            (self-loop included)
//   4. scatter edges into CSR (src, w=dinv[s]*dinv[d])
//   5. per layer: f32 register-tiled GEMM h=X@W, then wave-per-node
//      CSR gather-reduce with fused +bias, +self-loop, ReLU.
// R2: agg edge loop unrolled x4 (aligned int4/float4 index loads, 4
//     independent 512B H-row gathers in flight per wave) to fix the
//     latency-bound gather (VALUBusy was 14.5%, 1 load in flight).

constexpr int N_NODES = 100000;
constexpr int E_EDGES = 1600000;

__global__ __launch_bounds__(256) void count_kernel(
    const int* __restrict__ dst, int* __restrict__ cnt) {
  int e = blockIdx.x * 256 + threadIdx.x;
  if (e < E_EDGES) atomicAdd(&cnt[dst[e]], 1);
}

__global__ __launch_bounds__(1024) void scan_kernel(
    const int* __restrict__ cnt, int* __restrict__ rowptr) {
  __shared__ int part[1024];
  const int t = threadIdx.x;
  constexpr int CH = (N_NODES + 1023) / 1024;  // 98
  int b = t * CH;
  int e = min(b + CH, N_NODES);
  int s = 0;
  for (int i = b; i < e; ++i) s += cnt[i];
  part[t] = s;
  __syncthreads();
  for (int off = 1; off < 1024; off <<= 1) {
    int add = (t >= off) ? part[t - off] : 0;
    __syncthreads();
    part[t] += add;
    __syncthreads();
  }
  int run = part[t] - s;  // exclusive prefix of this chunk
  for (int i = b; i < e; ++i) { rowptr[i] = run; run += cnt[i]; }
  if (t == 1023) rowptr[N_NODES] = part[1023];
}

__global__ __launch_bounds__(256) void dinv_kernel(
    const int* __restrict__ cnt, float* __restrict__ dinv) {
  int i = blockIdx.x * 256 + threadIdx.x;
  if (i < N_NODES) dinv[i] = rsqrtf((float)cnt[i] + 1.0f);  // +1 self loop
}

__global__ __launch_bounds__(256) void scatter_kernel(
    const int* __restrict__ src, const int* __restrict__ dst,
    const int* __restrict__ rowptr, int* __restrict__ cursor,
    const float* __restrict__ dinv, int* __restrict__ eSrc,
    float* __restrict__ eW) {
  int e = blockIdx.x * 256 + threadIdx.x;
  if (e < E_EDGES) {
    int s = src[e], d = dst[e];
    int pos = rowptr[d] + atomicAdd(&cursor[d], 1);
    eSrc[pos] = s;
    eW[pos] = dinv[s] * dinv[d];
  }
}

// f32 GEMM: H[N, OC] = X[N, 128] @ W[128, OC]. Block tile 128 x OC,
// 16x16 thread grid, micro-tile 8 x (OC/16), K staged in LDS chunks of 32.
template <int OC>
__global__ __launch_bounds__(256) void gemm_kernel(
    const float* __restrict__ X, const float* __restrict__ W,
    float* __restrict__ H) {
  constexpr int K = 128;
  constexpr int KC = 32;
  constexpr int MC = OC / 16;  // cols per thread: 8 (OC=128) or 4 (OC=64)
  __shared__ float xs[KC][128 + 4];
  __shared__ float ws[KC][OC + 4];
  const int t = threadIdx.x;
  const int tx = t & 15, ty = t >> 4;
  const int row0 = blockIdx.x * 128;

  float acc[8][MC];
#pragma unroll
  for (int i = 0; i < 8; ++i)
#pragma unroll
    for (int j = 0; j < MC; ++j) acc[i][j] = 0.f;

  for (int kc = 0; kc < K; kc += KC) {
    __syncthreads();
    // X tile: 128 rows x KC -> xs[k][row] (transposed store)
    const float4* Xv = (const float4*)X;
#pragma unroll
    for (int it = 0; it < 4; ++it) {
      int idx = it * 256 + t;      // 0..1023
      int r = idx >> 3;            // KC/4 = 8 float4 per row
      int q = idx & 7;
      int gr = row0 + r;
      float4 v = make_float4(0.f, 0.f, 0.f, 0.f);
      if (gr < N_NODES) v = Xv[(size_t)gr * (K / 4) + (kc >> 2) + q];
      xs[q * 4 + 0][r] = v.x;
      xs[q * 4 + 1][r] = v.y;
      xs[q * 4 + 2][r] = v.z;
      xs[q * 4 + 3][r] = v.w;
    }
    // W tile: KC x OC -> ws[k][c] (direct, coalesced)
    const float4* Wv = (const float4*)W;
    constexpr int NW = KC * OC / 4 / 256;  // 4 or 2
#pragma unroll
    for (int it = 0; it < NW; ++it) {
      int idx = it * 256 + t;
      int kr = idx / (OC / 4);
      int cq = idx % (OC / 4);
      float4 v = Wv[(size_t)(kc + kr) * (OC / 4) + cq];
      *(float4*)&ws[kr][cq * 4] = v;
    }
    __syncthreads();
#pragma unroll
    for (int k = 0; k < KC; ++k) {
      float xr[8];
#pragma unroll
      for (int i = 0; i < 8; ++i) xr[i] = xs[k][ty * 8 + i];
      float wc[MC];
#pragma unroll
      for (int j = 0; j < MC; ++j) wc[j] = ws[k][tx * MC + j];
#pragma unroll
      for (int i = 0; i < 8; ++i)
#pragma unroll
        for (int j = 0; j < MC; ++j)
          acc[i][j] = fmaf(xr[i], wc[j], acc[i][j]);
    }
  }
#pragma unroll
  for (int i = 0; i < 8; ++i) {
    int gr = row0 + ty * 8 + i;
    if (gr < N_NODES) {
#pragma unroll
      for (int j = 0; j < MC; j += 4) {
        float4 v =
            make_float4(acc[i][j], acc[i][j + 1], acc[i][j + 2], acc[i][j + 3]);
        *(float4*)&H[(size_t)gr * OC + tx * MC + j] = v;
      }
    }
  }
}

// Wave-per-node CSR aggregation: Y[n] = relu(b + dinv[n]^2*H[n] +
// sum_e w_e * H[src_e]).  OC=128 -> float2/lane, OC=64 -> float/lane.
// Edge loop unrolled x4 with aligned int4/float4 loads of (src, w): four
// independent H-row gathers in flight per wave.
template <int OC>
__global__ __launch_bounds__(256) void agg_kernel(
    const float* __restrict__ H, const int* __restrict__ rowptr,
    const int* __restrict__ eSrc, const float* __restrict__ eW,
    const float* __restrict__ dinv, const float* __restrict__ bias,
    float* __restrict__ Y) {
  const int wave = threadIdx.x >> 6;
  const int lane = threadIdx.x & 63;
  const int n = blockIdx.x * 4 + wave;
  if (n >= N_NODES) return;
  const float dn = dinv[n];
  const float selfw = dn * dn;
  const int beg = rowptr[n], end = rowptr[n + 1];
  const int jal = min((beg + 3) & ~3, end);      // align to 16B for int4
  const int jend = jal + ((end - jal) & ~3);     // 4-wise main loop end

  if constexpr (OC == 128) {
    const float2* H2 = (const float2*)H;
    float2 hv = H2[(size_t)n * 64 + lane];
    float ax = hv.x * selfw, ay = hv.y * selfw;
    for (int j = beg; j < jal; ++j) {
      float w = eW[j];
      float2 v = H2[(size_t)eSrc[j] * 64 + lane];
      ax = fmaf(v.x, w, ax);
      ay = fmaf(v.y, w, ay);
    }
    for (int j = jal; j < jend; j += 4) {
      int4 s = *(const int4*)(eSrc + j);
      float4 w = *(const float4*)(eW + j);
      float2 v0 = H2[(size_t)s.x * 64 + lane];
      float2 v1 = H2[(size_t)s.y * 64 + lane];
      float2 v2 = H2[(size_t)s.z * 64 + lane];
      float2 v3 = H2[(size_t)s.w * 64 + lane];
      ax = fmaf(v0.x, w.x, ax); ay = fmaf(v0.y, w.x, ay);
      ax = fmaf(v1.x, w.y, ax); ay = fmaf(v1.y, w.y, ay);
      ax = fmaf(v2.x, w.z, ax); ay = fmaf(v2.y, w.z, ay);
      ax = fmaf(v3.x, w.w, ax); ay = fmaf(v3.y, w.w, ay);
    }
    for (int j = jend; j < end; ++j) {
      float w = eW[j];
      float2 v = H2[(size_t)eSrc[j] * 64 + lane];
      ax = fmaf(v.x, w, ax);
      ay = fmaf(v.y, w, ay);
    }
    float2 bb = ((const float2*)bias)[lane];
    float2 o;
    o.x = fmaxf(ax + bb.x, 0.f);
    o.y = fmaxf(ay + bb.y, 0.f);
    ((float2*)Y)[(size_t)n * 64 + lane] = o;
  } else {
    float a = H[(size_t)n * 64 + lane] * selfw;
    for (int j = beg; j < jal; ++j)
      a = fmaf(H[(size_t)eSrc[j] * 64 + lane], eW[j], a);
    for (int j = jal; j < jend; j += 4) {
      int4 s = *(const int4*)(eSrc + j);
      float4 w = *(const float4*)(eW + j);
      float v0 = H[(size_t)s.x * 64 + lane];
      float v1 = H[(size_t)s.y * 64 + lane];
      float v2 = H[(size_t)s.z * 64 + lane];
      float v3 = H[(size_t)s.w * 64 + lane];
      a = fmaf(v0, w.x, a);
      a = fmaf(v1, w.y, a);
      a = fmaf(v2, w.z, a);
      a = fmaf(v3, w.w, a);
    }
    for (int j = jend; j < end; ++j)
      a = fmaf(H[(size_t)eSrc[j] * 64 + lane], eW[j], a);
    Y[(size_t)n * 64 + lane] = fmaxf(a + bias[lane], 0.f);
  }
}

extern "C" void kernel_launch(void* const* d_in, const int* in_sizes, int n_in,
                              void* d_out, int out_size, void* d_ws,
                              size_t ws_size, hipStream_t stream) {
  const float* x = (const float*)d_in[0];
  const int* ei = (const int*)d_in[1];
  const float* W1 = (const float*)d_in[2];
  const float* b1 = (const float*)d_in[3];
  const float* W2 = (const float*)d_in[4];
  const float* b2 = (const float*)d_in[5];
  const float* W3 = (const float*)d_in[6];
  const float* b3 = (const float*)d_in[7];
  const int* src = ei;
  const int* dst = ei + E_EDGES;

  size_t off = 0;
  auto alloc = [&](size_t bytes) -> void* {
    void* p = (char*)d_ws + off;
    off += (bytes + 255) & ~(size_t)255;
    return p;
  };
  int* cnt = (int*)alloc((size_t)N_NODES * 4);
  int* rowptr = (int*)alloc((size_t)(N_NODES + 1) * 4);
  int* cursor = (int*)alloc((size_t)N_NODES * 4);
  float* dinv = (float*)alloc((size_t)N_NODES * 4);
  int* eSrc = (int*)alloc((size_t)E_EDGES * 4);
  float* eW = (float*)alloc((size_t)E_EDGES * 4);
  float* h = (float*)alloc((size_t)N_NODES * 128 * 4);
  float* A = (float*)alloc((size_t)N_NODES * 128 * 4);

  hipMemsetAsync(cnt, 0, (size_t)N_NODES * 4, stream);
  hipMemsetAsync(cursor, 0, (size_t)N_NODES * 4, stream);

  const int EB = (E_EDGES + 255) / 256;
  const int NB = (N_NODES + 255) / 256;
  count_kernel<<<EB, 256, 0, stream>>>(dst, cnt);
  scan_kernel<<<1, 1024, 0, stream>>>(cnt, rowptr);
  dinv_kernel<<<NB, 256, 0, stream>>>(cnt, dinv);
  scatter_kernel<<<EB, 256, 0, stream>>>(src, dst, rowptr, cursor, dinv, eSrc,
                                         eW);

  const int GB = (N_NODES + 127) / 128;  // 782
  const int AB = (N_NODES + 3) / 4;      // 25000

  gemm_kernel<128><<<GB, 256, 0, stream>>>(x, W1, h);
  agg_kernel<128><<<AB, 256, 0, stream>>>(h, rowptr, eSrc, eW, dinv, b1, A);
  gemm_kernel<128><<<GB, 256, 0, stream>>>(A, W2, h);
  agg_kernel<128><<<AB, 256, 0, stream>>>(h, rowptr, eSrc, eW, dinv, b2, A);
  gemm_kernel<64><<<GB, 256, 0, stream>>>(A, W3, h);
  agg_kernel<64><<<AB, 256, 0, stream>>>(h, rowptr, eSrc, eW, dinv, b3,
                                         (float*)d_out);
}

// Round 3
// 606.747 us; speedup vs baseline: 1.5231x; 1.2601x over previous
//
#include <hip/hip_runtime.h>
#include <hip/hip_bf16.h>

// GCN 3-layer forward for MI355X (gfx950).
// Pipeline per launch (deterministic up to atomic fp-sum order, within tol):
//   1. histogram in-degree over dst          (atomicAdd int)
//   2. 3-kernel multi-block exclusive scan -> CSR rowptr
//   3. dinv[i] = rsqrt(deg_i + 1)            (self-loop included)
//   4. scatter edges into CSR (src, w=dinv[s]*dinv[d])
//   5. per layer: f32 register-tiled GEMM h=X@W, then wave-per-node
//      CSR gather-reduce with fused +bias, +self-loop, ReLU.
// R2: agg edge loop unrolled (independent H-row gathers in flight).
// R3: scan parallelized (old single-block scan was 159 us at 0.16% occ,
//     latency-bound); agg unroll deepened 4 -> 8.

constexpr int N_NODES = 100000;
constexpr int E_EDGES = 1600000;
constexpr int SCAN_B = (N_NODES + 1023) / 1024;  // 98 blocks of 1024 elems

__global__ __launch_bounds__(256) void count_kernel(
    const int* __restrict__ dst, int* __restrict__ cnt) {
  int e = blockIdx.x * 256 + threadIdx.x;
  if (e < E_EDGES) atomicAdd(&cnt[dst[e]], 1);
}

// --- 3-kernel scan: cnt[N] -> rowptr[N+1] (exclusive) ---
__global__ __launch_bounds__(256) void scan_part_kernel(
    const int* __restrict__ cnt, int* __restrict__ bsum) {
  __shared__ int red[256];
  const int t = threadIdx.x;
  int base = blockIdx.x * 1024 + t * 4;  // N%4==0 -> all-or-nothing per thread
  int4 v = make_int4(0, 0, 0, 0);
  if (base < N_NODES) v = *(const int4*)(cnt + base);
  red[t] = v.x + v.y + v.z + v.w;
  __syncthreads();
  for (int off = 128; off > 0; off >>= 1) {
    if (t < off) red[t] += red[t + off];
    __syncthreads();
  }
  if (t == 0) bsum[blockIdx.x] = red[0];
}

__global__ __launch_bounds__(128) void scan_tops_kernel(
    const int* __restrict__ bsum, int* __restrict__ boff,
    int* __restrict__ rowptr) {
  __shared__ int part[128];
  const int t = threadIdx.x;
  int v = (t < SCAN_B) ? bsum[t] : 0;
  part[t] = v;
  __syncthreads();
  for (int off = 1; off < 128; off <<= 1) {
    int add = (t >= off) ? part[t - off] : 0;
    __syncthreads();
    part[t] += add;
    __syncthreads();
  }
  if (t < SCAN_B) boff[t] = part[t] - v;  // exclusive
  if (t == 127) rowptr[N_NODES] = part[127];
}

__global__ __launch_bounds__(256) void scan_write_kernel(
    const int* __restrict__ cnt, const int* __restrict__ boff,
    int* __restrict__ rowptr) {
  __shared__ int part[256];
  const int t = threadIdx.x;
  int base = blockIdx.x * 1024 + t * 4;
  int4 v = make_int4(0, 0, 0, 0);
  if (base < N_NODES) v = *(const int4*)(cnt + base);
  int s = v.x + v.y + v.z + v.w;
  part[t] = s;
  __syncthreads();
  for (int off = 1; off < 256; off <<= 1) {
    int add = (t >= off) ? part[t - off] : 0;
    __syncthreads();
    part[t] += add;
    __syncthreads();
  }
  if (base < N_NODES) {
    int run = boff[blockIdx.x] + part[t] - s;
    int4 o;
    o.x = run;
    o.y = run + v.x;
    o.z = run + v.x + v.y;
    o.w = run + v.x + v.y + v.z;
    *(int4*)(rowptr + base) = o;
  }
}

__global__ __launch_bounds__(256) void dinv_kernel(
    const int* __restrict__ cnt, float* __restrict__ dinv) {
  int i = blockIdx.x * 256 + threadIdx.x;
  if (i < N_NODES) dinv[i] = rsqrtf((float)cnt[i] + 1.0f);  // +1 self loop
}

__global__ __launch_bounds__(256) void scatter_kernel(
    const int* __restrict__ src, const int* __restrict__ dst,
    const int* __restrict__ rowptr, int* __restrict__ cursor,
    const float* __restrict__ dinv, int* __restrict__ eSrc,
    float* __restrict__ eW) {
  int e = blockIdx.x * 256 + threadIdx.x;
  if (e < E_EDGES) {
    int s = src[e], d = dst[e];
    int pos = rowptr[d] + atomicAdd(&cursor[d], 1);
    eSrc[pos] = s;
    eW[pos] = dinv[s] * dinv[d];
  }
}

// f32 GEMM: H[N, OC] = X[N, 128] @ W[128, OC]. Block tile 128 x OC,
// 16x16 thread grid, micro-tile 8 x (OC/16), K staged in LDS chunks of 32.
template <int OC>
__global__ __launch_bounds__(256) void gemm_kernel(
    const float* __restrict__ X, const float* __restrict__ W,
    float* __restrict__ H) {
  constexpr int K = 128;
  constexpr int KC = 32;
  constexpr int MC = OC / 16;  // cols per thread: 8 (OC=128) or 4 (OC=64)
  __shared__ float xs[KC][128 + 4];
  __shared__ float ws[KC][OC + 4];
  const int t = threadIdx.x;
  const int tx = t & 15, ty = t >> 4;
  const int row0 = blockIdx.x * 128;

  float acc[8][MC];
#pragma unroll
  for (int i = 0; i < 8; ++i)
#pragma unroll
    for (int j = 0; j < MC; ++j) acc[i][j] = 0.f;

  for (int kc = 0; kc < K; kc += KC) {
    __syncthreads();
    // X tile: 128 rows x KC -> xs[k][row] (transposed store)
    const float4* Xv = (const float4*)X;
#pragma unroll
    for (int it = 0; it < 4; ++it) {
      int idx = it * 256 + t;      // 0..1023
      int r = idx >> 3;            // KC/4 = 8 float4 per row
      int q = idx & 7;
      int gr = row0 + r;
      float4 v = make_float4(0.f, 0.f, 0.f, 0.f);
      if (gr < N_NODES) v = Xv[(size_t)gr * (K / 4) + (kc >> 2) + q];
      xs[q * 4 + 0][r] = v.x;
      xs[q * 4 + 1][r] = v.y;
      xs[q * 4 + 2][r] = v.z;
      xs[q * 4 + 3][r] = v.w;
    }
    // W tile: KC x OC -> ws[k][c] (direct, coalesced)
    const float4* Wv = (const float4*)W;
    constexpr int NW = KC * OC / 4 / 256;  // 4 or 2
#pragma unroll
    for (int it = 0; it < NW; ++it) {
      int idx = it * 256 + t;
      int kr = idx / (OC / 4);
      int cq = idx % (OC / 4);
      float4 v = Wv[(size_t)(kc + kr) * (OC / 4) + cq];
      *(float4*)&ws[kr][cq * 4] = v;
    }
    __syncthreads();
#pragma unroll
    for (int k = 0; k < KC; ++k) {
      float xr[8];
#pragma unroll
      for (int i = 0; i < 8; ++i) xr[i] = xs[k][ty * 8 + i];
      float wc[MC];
#pragma unroll
      for (int j = 0; j < MC; ++j) wc[j] = ws[k][tx * MC + j];
#pragma unroll
      for (int i = 0; i < 8; ++i)
#pragma unroll
        for (int j = 0; j < MC; ++j)
          acc[i][j] = fmaf(xr[i], wc[j], acc[i][j]);
    }
  }
#pragma unroll
  for (int i = 0; i < 8; ++i) {
    int gr = row0 + ty * 8 + i;
    if (gr < N_NODES) {
#pragma unroll
      for (int j = 0; j < MC; j += 4) {
        float4 v =
            make_float4(acc[i][j], acc[i][j + 1], acc[i][j + 2], acc[i][j + 3]);
        *(float4*)&H[(size_t)gr * OC + tx * MC + j] = v;
      }
    }
  }
}

// Wave-per-node CSR aggregation: Y[n] = relu(b + dinv[n]^2*H[n] +
// sum_e w_e * H[src_e]).  OC=128 -> float2/lane, OC=64 -> float/lane.
// Edge loop unrolled x8 (two aligned int4/float4 index loads): eight
// independent H-row gathers in flight per wave.
template <int OC>
__global__ __launch_bounds__(256) void agg_kernel(
    const float* __restrict__ H, const int* __restrict__ rowptr,
    const int* __restrict__ eSrc, const float* __restrict__ eW,
    const float* __restrict__ dinv, const float* __restrict__ bias,
    float* __restrict__ Y) {
  const int wave = threadIdx.x >> 6;
  const int lane = threadIdx.x & 63;
  const int n = blockIdx.x * 4 + wave;
  if (n >= N_NODES) return;
  const float dn = dinv[n];
  const float selfw = dn * dn;
  const int beg = rowptr[n], end = rowptr[n + 1];
  const int jal = min((beg + 3) & ~3, end);      // align to 16B for int4
  const int jend = jal + ((end - jal) & ~7);     // 8-wise main loop end
  const int jend4 = jend + ((end - jend) & ~3);  // 4-wise cleanup end

  if constexpr (OC == 128) {
    const float2* H2 = (const float2*)H;
    float2 hv = H2[(size_t)n * 64 + lane];
    float ax = hv.x * selfw, ay = hv.y * selfw;
    for (int j = beg; j < jal; ++j) {
      float w = eW[j];
      float2 v = H2[(size_t)eSrc[j] * 64 + lane];
      ax = fmaf(v.x, w, ax);
      ay = fmaf(v.y, w, ay);
    }
    for (int j = jal; j < jend; j += 8) {
      int4 s0 = *(const int4*)(eSrc + j);
      int4 s1 = *(const int4*)(eSrc + j + 4);
      float4 w0 = *(const float4*)(eW + j);
      float4 w1 = *(const float4*)(eW + j + 4);
      float2 v0 = H2[(size_t)s0.x * 64 + lane];
      float2 v1 = H2[(size_t)s0.y * 64 + lane];
      float2 v2 = H2[(size_t)s0.z * 64 + lane];
      float2 v3 = H2[(size_t)s0.w * 64 + lane];
      float2 v4 = H2[(size_t)s1.x * 64 + lane];
      float2 v5 = H2[(size_t)s1.y * 64 + lane];
      float2 v6 = H2[(size_t)s1.z * 64 + lane];
      float2 v7 = H2[(size_t)s1.w * 64 + lane];
      ax = fmaf(v0.x, w0.x, ax); ay = fmaf(v0.y, w0.x, ay);
      ax = fmaf(v1.x, w0.y, ax); ay = fmaf(v1.y, w0.y, ay);
      ax = fmaf(v2.x, w0.z, ax); ay = fmaf(v2.y, w0.z, ay);
      ax = fmaf(v3.x, w0.w, ax); ay = fmaf(v3.y, w0.w, ay);
      ax = fmaf(v4.x, w1.x, ax); ay = fmaf(v4.y, w1.x, ay);
      ax = fmaf(v5.x, w1.y, ax); ay = fmaf(v5.y, w1.y, ay);
      ax = fmaf(v6.x, w1.z, ax); ay = fmaf(v6.y, w1.z, ay);
      ax = fmaf(v7.x, w1.w, ax); ay = fmaf(v7.y, w1.w, ay);
    }
    for (int j = jend; j < jend4; j += 4) {
      int4 s = *(const int4*)(eSrc + j);
      float4 w = *(const float4*)(eW + j);
      float2 v0 = H2[(size_t)s.x * 64 + lane];
      float2 v1 = H2[(size_t)s.y * 64 + lane];
      float2 v2 = H2[(size_t)s.z * 64 + lane];
      float2 v3 = H2[(size_t)s.w * 64 + lane];
      ax = fmaf(v0.x, w.x, ax); ay = fmaf(v0.y, w.x, ay);
      ax = fmaf(v1.x, w.y, ax); ay = fmaf(v1.y, w.y, ay);
      ax = fmaf(v2.x, w.z, ax); ay = fmaf(v2.y, w.z, ay);
      ax = fmaf(v3.x, w.w, ax); ay = fmaf(v3.y, w.w, ay);
    }
    for (int j = jend4; j < end; ++j) {
      float w = eW[j];
      float2 v = H2[(size_t)eSrc[j] * 64 + lane];
      ax = fmaf(v.x, w, ax);
      ay = fmaf(v.y, w, ay);
    }
    float2 bb = ((const float2*)bias)[lane];
    float2 o;
    o.x = fmaxf(ax + bb.x, 0.f);
    o.y = fmaxf(ay + bb.y, 0.f);
    ((float2*)Y)[(size_t)n * 64 + lane] = o;
  } else {
    float a = H[(size_t)n * 64 + lane] * selfw;
    for (int j = beg; j < jal; ++j)
      a = fmaf(H[(size_t)eSrc[j] * 64 + lane], eW[j], a);
    for (int j = jal; j < jend; j += 8) {
      int4 s0 = *(const int4*)(eSrc + j);
      int4 s1 = *(const int4*)(eSrc + j + 4);
      float4 w0 = *(const float4*)(eW + j);
      float4 w1 = *(const float4*)(eW + j + 4);
      float v0 = H[(size_t)s0.x * 64 + lane];
      float v1 = H[(size_t)s0.y * 64 + lane];
      float v2 = H[(size_t)s0.z * 64 + lane];
      float v3 = H[(size_t)s0.w * 64 + lane];
      float v4 = H[(size_t)s1.x * 64 + lane];
      float v5 = H[(size_t)s1.y * 64 + lane];
      float v6 = H[(size_t)s1.z * 64 + lane];
      float v7 = H[(size_t)s1.w * 64 + lane];
      a = fmaf(v0, w0.x, a);
      a = fmaf(v1, w0.y, a);
      a = fmaf(v2, w0.z, a);
      a = fmaf(v3, w0.w, a);
      a = fmaf(v4, w1.x, a);
      a = fmaf(v5, w1.y, a);
      a = fmaf(v6, w1.z, a);
      a = fmaf(v7, w1.w, a);
    }
    for (int j = jend; j < jend4; j += 4) {
      int4 s = *(const int4*)(eSrc + j);
      float4 w = *(const float4*)(eW + j);
      float v0 = H[(size_t)s.x * 64 + lane];
      float v1 = H[(size_t)s.y * 64 + lane];
      float v2 = H[(size_t)s.z * 64 + lane];
      float v3 = H[(size_t)s.w * 64 + lane];
      a = fmaf(v0, w.x, a);
      a = fmaf(v1, w.y, a);
      a = fmaf(v2, w.z, a);
      a = fmaf(v3, w.w, a);
    }
    for (int j = jend4; j < end; ++j)
      a = fmaf(H[(size_t)eSrc[j] * 64 + lane], eW[j], a);
    Y[(size_t)n * 64 + lane] = fmaxf(a + bias[lane], 0.f);
  }
}

extern "C" void kernel_launch(void* const* d_in, const int* in_sizes, int n_in,
                              void* d_out, int out_size, void* d_ws,
                              size_t ws_size, hipStream_t stream) {
  const float* x = (const float*)d_in[0];
  const int* ei = (const int*)d_in[1];
  const float* W1 = (const float*)d_in[2];
  const float* b1 = (const float*)d_in[3];
  const float* W2 = (const float*)d_in[4];
  const float* b2 = (const float*)d_in[5];
  const float* W3 = (const float*)d_in[6];
  const float* b3 = (const float*)d_in[7];
  const int* src = ei;
  const int* dst = ei + E_EDGES;

  size_t off = 0;
  auto alloc = [&](size_t bytes) -> void* {
    void* p = (char*)d_ws + off;
    off += (bytes + 255) & ~(size_t)255;
    return p;
  };
  int* cnt = (int*)alloc((size_t)N_NODES * 4);
  int* rowptr = (int*)alloc((size_t)(N_NODES + 1) * 4);
  int* cursor = (int*)alloc((size_t)N_NODES * 4);
  float* dinv = (float*)alloc((size_t)N_NODES * 4);
  int* bsum = (int*)alloc((size_t)SCAN_B * 4);
  int* boff = (int*)alloc((size_t)SCAN_B * 4);
  int* eSrc = (int*)alloc((size_t)E_EDGES * 4);
  float* eW = (float*)alloc((size_t)E_EDGES * 4);
  float* h = (float*)alloc((size_t)N_NODES * 128 * 4);
  float* A = (float*)alloc((size_t)N_NODES * 128 * 4);

  hipMemsetAsync(cnt, 0, (size_t)N_NODES * 4, stream);
  hipMemsetAsync(cursor, 0, (size_t)N_NODES * 4, stream);

  const int EB = (E_EDGES + 255) / 256;
  const int NB = (N_NODES + 255) / 256;
  count_kernel<<<EB, 256, 0, stream>>>(dst, cnt);
  scan_part_kernel<<<SCAN_B, 256, 0, stream>>>(cnt, bsum);
  scan_tops_kernel<<<1, 128, 0, stream>>>(bsum, boff, rowptr);
  scan_write_kernel<<<SCAN_B, 256, 0, stream>>>(cnt, boff, rowptr);
  dinv_kernel<<<NB, 256, 0, stream>>>(cnt, dinv);
  scatter_kernel<<<EB, 256, 0, stream>>>(src, dst, rowptr, cursor, dinv, eSrc,
                                         eW);

  const int GB = (N_NODES + 127) / 128;  // 782
  const int AB = (N_NODES + 3) / 4;      // 25000

  gemm_kernel<128><<<GB, 256, 0, stream>>>(x, W1, h);
  agg_kernel<128><<<AB, 256, 0, stream>>>(h, rowptr, eSrc, eW, dinv, b1, A);
  gemm_kernel<128><<<GB, 256, 0, stream>>>(A, W2, h);
  agg_kernel<128><<<AB, 256, 0, stream>>>(h, rowptr, eSrc, eW, dinv, b2, A);
  gemm_kernel<64><<<GB, 256, 0, stream>>>(A, W3, h);
  agg_kernel<64><<<AB, 256, 0, stream>>>(h, rowptr, eSrc, eW, dinv, b3,
                                         (float*)d_out);
}

// Round 4
// 569.858 us; speedup vs baseline: 1.6217x; 1.0647x over previous
//
#include <hip/hip_runtime.h>
#include <hip/hip_bf16.h>

// GCN 3-layer forward for MI355X (gfx950).
//   1. histogram in-degree over dst          (atomicAdd int)
//   2. 3-kernel multi-block exclusive scan -> CSR rowptr
//   3. dinv[i] = rsqrt(deg_i + 1)            (self-loop included)
//   4. scatter edges into CSR (src, w=dinv[s]*dinv[d])
//   5. per layer: split-bf16 MFMA GEMM h=X@W, then wave-per-node
//      CSR gather-reduce with fused +bias, +self-loop, ReLU.
// R2: agg edge loop unrolled (independent H-row gathers in flight).
// R3: scan parallelized; agg unroll 4 -> 8.
// R4: GEMM moved to matrix cores via split-bf16 (x = hi + lo, 3 MFMAs:
//     hi*hi + hi*lo + lo*hi; ~2^-17 rel err, f32-accumulate). W pre-packed
//     in fragment-linear layout. agg unroll 8 -> 16 (MLP diagnostic).

constexpr int N_NODES = 100000;
constexpr int E_EDGES = 1600000;
constexpr int SCAN_B = (N_NODES + 1023) / 1024;  // 98 blocks of 1024 elems

typedef short short8 __attribute__((ext_vector_type(8)));
typedef float f32x4 __attribute__((ext_vector_type(4)));

__global__ __launch_bounds__(256) void count_kernel(
    const int* __restrict__ dst, int* __restrict__ cnt) {
  int e = blockIdx.x * 256 + threadIdx.x;
  if (e < E_EDGES) atomicAdd(&cnt[dst[e]], 1);
}

// --- 3-kernel scan: cnt[N] -> rowptr[N+1] (exclusive) ---
__global__ __launch_bounds__(256) void scan_part_kernel(
    const int* __restrict__ cnt, int* __restrict__ bsum) {
  __shared__ int red[256];
  const int t = threadIdx.x;
  int base = blockIdx.x * 1024 + t * 4;
  int4 v = make_int4(0, 0, 0, 0);
  if (base < N_NODES) v = *(const int4*)(cnt + base);
  red[t] = v.x + v.y + v.z + v.w;
  __syncthreads();
  for (int off = 128; off > 0; off >>= 1) {
    if (t < off) red[t] += red[t + off];
    __syncthreads();
  }
  if (t == 0) bsum[blockIdx.x] = red[0];
}

__global__ __launch_bounds__(128) void scan_tops_kernel(
    const int* __restrict__ bsum, int* __restrict__ boff,
    int* __restrict__ rowptr) {
  __shared__ int part[128];
  const int t = threadIdx.x;
  int v = (t < SCAN_B) ? bsum[t] : 0;
  part[t] = v;
  __syncthreads();
  for (int off = 1; off < 128; off <<= 1) {
    int add = (t >= off) ? part[t - off] : 0;
    __syncthreads();
    part[t] += add;
    __syncthreads();
  }
  if (t < SCAN_B) boff[t] = part[t] - v;  // exclusive
  if (t == 127) rowptr[N_NODES] = part[127];
}

__global__ __launch_bounds__(256) void scan_write_kernel(
    const int* __restrict__ cnt, const int* __restrict__ boff,
    int* __restrict__ rowptr) {
  __shared__ int part[256];
  const int t = threadIdx.x;
  int base = blockIdx.x * 1024 + t * 4;
  int4 v = make_int4(0, 0, 0, 0);
  if (base < N_NODES) v = *(const int4*)(cnt + base);
  int s = v.x + v.y + v.z + v.w;
  part[t] = s;
  __syncthreads();
  for (int off = 1; off < 256; off <<= 1) {
    int add = (t >= off) ? part[t - off] : 0;
    __syncthreads();
    part[t] += add;
    __syncthreads();
  }
  if (base < N_NODES) {
    int run = boff[blockIdx.x] + part[t] - s;
    int4 o;
    o.x = run;
    o.y = run + v.x;
    o.z = run + v.x + v.y;
    o.w = run + v.x + v.y + v.z;
    *(int4*)(rowptr + base) = o;
  }
}

__global__ __launch_bounds__(256) void dinv_kernel(
    const int* __restrict__ cnt, float* __restrict__ dinv) {
  int i = blockIdx.x * 256 + threadIdx.x;
  if (i < N_NODES) dinv[i] = rsqrtf((float)cnt[i] + 1.0f);  // +1 self loop
}

__global__ __launch_bounds__(256) void scatter_kernel(
    const int* __restrict__ src, const int* __restrict__ dst,
    const int* __restrict__ rowptr, int* __restrict__ cursor,
    const float* __restrict__ dinv, int* __restrict__ eSrc,
    float* __restrict__ eW) {
  int e = blockIdx.x * 256 + threadIdx.x;
  if (e < E_EDGES) {
    int s = src[e], d = dst[e];
    int pos = rowptr[d] + atomicAdd(&cursor[d], 1);
    eSrc[pos] = s;
    eW[pos] = dinv[s] * dinv[d];
  }
}

// bf16 split helpers (manual RNE; inputs finite)
__device__ inline ushort bf_round(float x) {
  uint u = __float_as_uint(x);
  return (ushort)((u + 0x7FFFu + ((u >> 16) & 1u)) >> 16);
}
__device__ inline ushort bf_split(float x, float* rem) {
  ushort h = bf_round(x);
  *rem = x - __uint_as_float((uint)h << 16);
  return h;
}

// Pack W [128][OC] f32 into fragment-linear hi/lo bf16:
// chunk id = ((nt*4 + ks)*4 + g)*16 + col holds 8 bf16:
//   W[ks*32 + g*8 + j][nt*16 + col], j = 0..7.
template <int OC>
__global__ __launch_bounds__(256) void packw_kernel(
    const float* __restrict__ W, ushort* __restrict__ hi,
    ushort* __restrict__ lo) {
  int id = blockIdx.x * 256 + threadIdx.x;
  if (id >= OC * 16) return;  // (OC/16)*4*4*16 chunks
  int col = id & 15;
  int g = (id >> 4) & 3;
  int ks = (id >> 6) & 3;
  int nt = id >> 8;
  int k0 = ks * 32 + g * 8;
  int n = nt * 16 + col;
  ushort h8[8], l8[8];
#pragma unroll
  for (int j = 0; j < 8; ++j) {
    float rem;
    h8[j] = bf_split(W[(size_t)(k0 + j) * OC + n], &rem);
    l8[j] = bf_round(rem);
  }
  size_t base = (size_t)id * 8;
#pragma unroll
  for (int j = 0; j < 8; ++j) {
    hi[base + j] = h8[j];
    lo[base + j] = l8[j];
  }
}

// Split-bf16 MFMA GEMM: H[N, OC] = X[N, 128] @ W[128, OC].
// 4 waves/block, 16 rows/wave (M-tile 64). W (packed hi/lo) staged in LDS;
// A-fragments loaded direct from global (X is L2/L3-resident) and split
// to hi/lo in registers. 3 MFMAs per (nt, ks): hi*hi + hi*lo + lo*hi.
template <int OC>
__global__ __launch_bounds__(256) void gemm_kernel(
    const float* __restrict__ X, const ushort* __restrict__ Whi,
    const ushort* __restrict__ Wlo, float* __restrict__ H) {
  constexpr int NT = OC / 16;
  __shared__ ushort sWhi[OC * 128];
  __shared__ ushort sWlo[OC * 128];
  const int t = threadIdx.x;
  {  // stage packed W (contiguous, coalesced uint4 copies)
    const uint4* gh = (const uint4*)Whi;
    const uint4* gl = (const uint4*)Wlo;
    uint4* sh = (uint4*)sWhi;
    uint4* sl = (uint4*)sWlo;
    for (int i = t; i < OC * 128 / 8; i += 256) {
      sh[i] = gh[i];
      sl[i] = gl[i];
    }
  }
  const int wid = t >> 6;
  const int lane = t & 63;
  const int row = blockIdx.x * 64 + wid * 16 + (lane & 15);
  const bool ok = row < N_NODES;
  const int g = lane >> 4;  // k-group 0..3

  // Load + split A fragments for all 4 k-steps
  short8 ahi[4], alo[4];
  const float* xr = X + (size_t)row * 128;
#pragma unroll
  for (int ks = 0; ks < 4; ++ks) {
    float f[8];
    if (ok) {
      float4 f0 = *(const float4*)(xr + ks * 32 + g * 8);
      float4 f1 = *(const float4*)(xr + ks * 32 + g * 8 + 4);
      f[0] = f0.x; f[1] = f0.y; f[2] = f0.z; f[3] = f0.w;
      f[4] = f1.x; f[5] = f1.y; f[6] = f1.z; f[7] = f1.w;
    } else {
#pragma unroll
      for (int j = 0; j < 8; ++j) f[j] = 0.f;
    }
    union { short8 v; ushort u[8]; } h, l;
#pragma unroll
    for (int j = 0; j < 8; ++j) {
      float rem;
      h.u[j] = bf_split(f[j], &rem);
      l.u[j] = bf_round(rem);
    }
    ahi[ks] = h.v;
    alo[ks] = l.v;
  }
  __syncthreads();

#pragma unroll
  for (int nt = 0; nt < NT; ++nt) {
    f32x4 acc = {0.f, 0.f, 0.f, 0.f};
#pragma unroll
    for (int ks = 0; ks < 4; ++ks) {
      int off = (((nt * 4 + ks) * 4 + g) * 16 + (lane & 15)) * 8;
      short8 bhi = *(const short8*)&sWhi[off];
      short8 blo = *(const short8*)&sWlo[off];
      acc = __builtin_amdgcn_mfma_f32_16x16x32_bf16(alo[ks], bhi, acc, 0, 0, 0);
      acc = __builtin_amdgcn_mfma_f32_16x16x32_bf16(ahi[ks], blo, acc, 0, 0, 0);
      acc = __builtin_amdgcn_mfma_f32_16x16x32_bf16(ahi[ks], bhi, acc, 0, 0, 0);
    }
    // C: col = lane&15, row_in_tile = (lane>>4)*4 + r
#pragma unroll
    for (int r = 0; r < 4; ++r) {
      int rr = blockIdx.x * 64 + wid * 16 + g * 4 + r;
      if (rr < N_NODES) H[(size_t)rr * OC + nt * 16 + (lane & 15)] = acc[r];
    }
  }
}

// Wave-per-node CSR aggregation: Y[n] = relu(b + dinv[n]^2*H[n] +
// sum_e w_e * H[src_e]).  OC=128 -> float2/lane, OC=64 -> float/lane.
// Edge loop unrolled x16 (aligned int4/float4 index loads): sixteen
// independent H-row gathers in flight per wave.
template <int OC>
__global__ __launch_bounds__(256) void agg_kernel(
    const float* __restrict__ H, const int* __restrict__ rowptr,
    const int* __restrict__ eSrc, const float* __restrict__ eW,
    const float* __restrict__ dinv, const float* __restrict__ bias,
    float* __restrict__ Y) {
  const int wave = threadIdx.x >> 6;
  const int lane = threadIdx.x & 63;
  const int n = blockIdx.x * 4 + wave;
  if (n >= N_NODES) return;
  const float dn = dinv[n];
  const float selfw = dn * dn;
  const int beg = rowptr[n], end = rowptr[n + 1];
  const int jal = min((beg + 3) & ~3, end);        // align to 16B for int4
  const int j16 = jal + ((end - jal) & ~15);       // 16-wise main loop end
  const int j8 = j16 + ((end - j16) & ~7);         // 8-wise
  const int j4 = j8 + ((end - j8) & ~3);           // 4-wise

  if constexpr (OC == 128) {
    const float2* H2 = (const float2*)H;
    float2 hv = H2[(size_t)n * 64 + lane];
    float ax = hv.x * selfw, ay = hv.y * selfw;
    for (int j = beg; j < jal; ++j) {
      float w = eW[j];
      float2 v = H2[(size_t)eSrc[j] * 64 + lane];
      ax = fmaf(v.x, w, ax);
      ay = fmaf(v.y, w, ay);
    }
    for (int j = jal; j < j16; j += 16) {
      int4 s0 = *(const int4*)(eSrc + j);
      int4 s1 = *(const int4*)(eSrc + j + 4);
      int4 s2 = *(const int4*)(eSrc + j + 8);
      int4 s3 = *(const int4*)(eSrc + j + 12);
      float4 w0 = *(const float4*)(eW + j);
      float4 w1 = *(const float4*)(eW + j + 4);
      float4 w2 = *(const float4*)(eW + j + 8);
      float4 w3 = *(const float4*)(eW + j + 12);
      float2 v0 = H2[(size_t)s0.x * 64 + lane];
      float2 v1 = H2[(size_t)s0.y * 64 + lane];
      float2 v2 = H2[(size_t)s0.z * 64 + lane];
      float2 v3 = H2[(size_t)s0.w * 64 + lane];
      float2 v4 = H2[(size_t)s1.x * 64 + lane];
      float2 v5 = H2[(size_t)s1.y * 64 + lane];
      float2 v6 = H2[(size_t)s1.z * 64 + lane];
      float2 v7 = H2[(size_t)s1.w * 64 + lane];
      float2 v8 = H2[(size_t)s2.x * 64 + lane];
      float2 v9 = H2[(size_t)s2.y * 64 + lane];
      float2 va = H2[(size_t)s2.z * 64 + lane];
      float2 vb = H2[(size_t)s2.w * 64 + lane];
      float2 vc = H2[(size_t)s3.x * 64 + lane];
      float2 vd = H2[(size_t)s3.y * 64 + lane];
      float2 ve = H2[(size_t)s3.z * 64 + lane];
      float2 vf = H2[(size_t)s3.w * 64 + lane];
      ax = fmaf(v0.x, w0.x, ax); ay = fmaf(v0.y, w0.x, ay);
      ax = fmaf(v1.x, w0.y, ax); ay = fmaf(v1.y, w0.y, ay);
      ax = fmaf(v2.x, w0.z, ax); ay = fmaf(v2.y, w0.z, ay);
      ax = fmaf(v3.x, w0.w, ax); ay = fmaf(v3.y, w0.w, ay);
      ax = fmaf(v4.x, w1.x, ax); ay = fmaf(v4.y, w1.x, ay);
      ax = fmaf(v5.x, w1.y, ax); ay = fmaf(v5.y, w1.y, ay);
      ax = fmaf(v6.x, w1.z, ax); ay = fmaf(v6.y, w1.z, ay);
      ax = fmaf(v7.x, w1.w, ax); ay = fmaf(v7.y, w1.w, ay);
      ax = fmaf(v8.x, w2.x, ax); ay = fmaf(v8.y, w2.x, ay);
      ax = fmaf(v9.x, w2.y, ax); ay = fmaf(v9.y, w2.y, ay);
      ax = fmaf(va.x, w2.z, ax); ay = fmaf(va.y, w2.z, ay);
      ax = fmaf(vb.x, w2.w, ax); ay = fmaf(vb.y, w2.w, ay);
      ax = fmaf(vc.x, w3.x, ax); ay = fmaf(vc.y, w3.x, ay);
      ax = fmaf(vd.x, w3.y, ax); ay = fmaf(vd.y, w3.y, ay);
      ax = fmaf(ve.x, w3.z, ax); ay = fmaf(ve.y, w3.z, ay);
      ax = fmaf(vf.x, w3.w, ax); ay = fmaf(vf.y, w3.w, ay);
    }
    for (int j = j16; j < j8; j += 8) {
      int4 s0 = *(const int4*)(eSrc + j);
      int4 s1 = *(const int4*)(eSrc + j + 4);
      float4 w0 = *(const float4*)(eW + j);
      float4 w1 = *(const float4*)(eW + j + 4);
      float2 v0 = H2[(size_t)s0.x * 64 + lane];
      float2 v1 = H2[(size_t)s0.y * 64 + lane];
      float2 v2 = H2[(size_t)s0.z * 64 + lane];
      float2 v3 = H2[(size_t)s0.w * 64 + lane];
      float2 v4 = H2[(size_t)s1.x * 64 + lane];
      float2 v5 = H2[(size_t)s1.y * 64 + lane];
      float2 v6 = H2[(size_t)s1.z * 64 + lane];
      float2 v7 = H2[(size_t)s1.w * 64 + lane];
      ax = fmaf(v0.x, w0.x, ax); ay = fmaf(v0.y, w0.x, ay);
      ax = fmaf(v1.x, w0.y, ax); ay = fmaf(v1.y, w0.y, ay);
      ax = fmaf(v2.x, w0.z, ax); ay = fmaf(v2.y, w0.z, ay);
      ax = fmaf(v3.x, w0.w, ax); ay = fmaf(v3.y, w0.w, ay);
      ax = fmaf(v4.x, w1.x, ax); ay = fmaf(v4.y, w1.x, ay);
      ax = fmaf(v5.x, w1.y, ax); ay = fmaf(v5.y, w1.y, ay);
      ax = fmaf(v6.x, w1.z, ax); ay = fmaf(v6.y, w1.z, ay);
      ax = fmaf(v7.x, w1.w, ax); ay = fmaf(v7.y, w1.w, ay);
    }
    for (int j = j8; j < j4; j += 4) {
      int4 s = *(const int4*)(eSrc + j);
      float4 w = *(const float4*)(eW + j);
      float2 v0 = H2[(size_t)s.x * 64 + lane];
      float2 v1 = H2[(size_t)s.y * 64 + lane];
      float2 v2 = H2[(size_t)s.z * 64 + lane];
      float2 v3 = H2[(size_t)s.w * 64 + lane];
      ax = fmaf(v0.x, w.x, ax); ay = fmaf(v0.y, w.x, ay);
      ax = fmaf(v1.x, w.y, ax); ay = fmaf(v1.y, w.y, ay);
      ax = fmaf(v2.x, w.z, ax); ay = fmaf(v2.y, w.z, ay);
      ax = fmaf(v3.x, w.w, ax); ay = fmaf(v3.y, w.w, ay);
    }
    for (int j = j4; j < end; ++j) {
      float w = eW[j];
      float2 v = H2[(size_t)eSrc[j] * 64 + lane];
      ax = fmaf(v.x, w, ax);
      ay = fmaf(v.y, w, ay);
    }
    float2 bb = ((const float2*)bias)[lane];
    float2 o;
    o.x = fmaxf(ax + bb.x, 0.f);
    o.y = fmaxf(ay + bb.y, 0.f);
    ((float2*)Y)[(size_t)n * 64 + lane] = o;
  } else {
    float a = H[(size_t)n * 64 + lane] * selfw;
    for (int j = beg; j < jal; ++j)
      a = fmaf(H[(size_t)eSrc[j] * 64 + lane], eW[j], a);
    for (int j = jal; j < j16; j += 16) {
      int4 s0 = *(const int4*)(eSrc + j);
      int4 s1 = *(const int4*)(eSrc + j + 4);
      int4 s2 = *(const int4*)(eSrc + j + 8);
      int4 s3 = *(const int4*)(eSrc + j + 12);
      float4 w0 = *(const float4*)(eW + j);
      float4 w1 = *(const float4*)(eW + j + 4);
      float4 w2 = *(const float4*)(eW + j + 8);
      float4 w3 = *(const float4*)(eW + j + 12);
      float v0 = H[(size_t)s0.x * 64 + lane];
      float v1 = H[(size_t)s0.y * 64 + lane];
      float v2 = H[(size_t)s0.z * 64 + lane];
      float v3 = H[(size_t)s0.w * 64 + lane];
      float v4 = H[(size_t)s1.x * 64 + lane];
      float v5 = H[(size_t)s1.y * 64 + lane];
      float v6 = H[(size_t)s1.z * 64 + lane];
      float v7 = H[(size_t)s1.w * 64 + lane];
      float v8 = H[(size_t)s2.x * 64 + lane];
      float v9 = H[(size_t)s2.y * 64 + lane];
      float va = H[(size_t)s2.z * 64 + lane];
      float vb = H[(size_t)s2.w * 64 + lane];
      float vc = H[(size_t)s3.x * 64 + lane];
      float vd = H[(size_t)s3.y * 64 + lane];
      float ve = H[(size_t)s3.z * 64 + lane];
      float vf = H[(size_t)s3.w * 64 + lane];
      a = fmaf(v0, w0.x, a); a = fmaf(v1, w0.y, a);
      a = fmaf(v2, w0.z, a); a = fmaf(v3, w0.w, a);
      a = fmaf(v4, w1.x, a); a = fmaf(v5, w1.y, a);
      a = fmaf(v6, w1.z, a); a = fmaf(v7, w1.w, a);
      a = fmaf(v8, w2.x, a); a = fmaf(v9, w2.y, a);
      a = fmaf(va, w2.z, a); a = fmaf(vb, w2.w, a);
      a = fmaf(vc, w3.x, a); a = fmaf(vd, w3.y, a);
      a = fmaf(ve, w3.z, a); a = fmaf(vf, w3.w, a);
    }
    for (int j = j16; j < j8; j += 8) {
      int4 s0 = *(const int4*)(eSrc + j);
      int4 s1 = *(const int4*)(eSrc + j + 4);
      float4 w0 = *(const float4*)(eW + j);
      float4 w1 = *(const float4*)(eW + j + 4);
      float v0 = H[(size_t)s0.x * 64 + lane];
      float v1 = H[(size_t)s0.y * 64 + lane];
      float v2 = H[(size_t)s0.z * 64 + lane];
      float v3 = H[(size_t)s0.w * 64 + lane];
      float v4 = H[(size_t)s1.x * 64 + lane];
      float v5 = H[(size_t)s1.y * 64 + lane];
      float v6 = H[(size_t)s1.z * 64 + lane];
      float v7 = H[(size_t)s1.w * 64 + lane];
      a = fmaf(v0, w0.x, a); a = fmaf(v1, w0.y, a);
      a = fmaf(v2, w0.z, a); a = fmaf(v3, w0.w, a);
      a = fmaf(v4, w1.x, a); a = fmaf(v5, w1.y, a);
      a = fmaf(v6, w1.z, a); a = fmaf(v7, w1.w, a);
    }
    for (int j = j8; j < j4; j += 4) {
      int4 s = *(const int4*)(eSrc + j);
      float4 w = *(const float4*)(eW + j);
      float v0 = H[(size_t)s.x * 64 + lane];
      float v1 = H[(size_t)s.y * 64 + lane];
      float v2 = H[(size_t)s.z * 64 + lane];
      float v3 = H[(size_t)s.w * 64 + lane];
      a = fmaf(v0, w.x, a); a = fmaf(v1, w.y, a);
      a = fmaf(v2, w.z, a); a = fmaf(v3, w.w, a);
    }
    for (int j = j4; j < end; ++j)
      a = fmaf(H[(size_t)eSrc[j] * 64 + lane], eW[j], a);
    Y[(size_t)n * 64 + lane] = fmaxf(a + bias[lane], 0.f);
  }
}

extern "C" void kernel_launch(void* const* d_in, const int* in_sizes, int n_in,
                              void* d_out, int out_size, void* d_ws,
                              size_t ws_size, hipStream_t stream) {
  const float* x = (const float*)d_in[0];
  const int* ei = (const int*)d_in[1];
  const float* W1 = (const float*)d_in[2];
  const float* b1 = (const float*)d_in[3];
  const float* W2 = (const float*)d_in[4];
  const float* b2 = (const float*)d_in[5];
  const float* W3 = (const float*)d_in[6];
  const float* b3 = (const float*)d_in[7];
  const int* src = ei;
  const int* dst = ei + E_EDGES;

  size_t off = 0;
  auto alloc = [&](size_t bytes) -> void* {
    void* p = (char*)d_ws + off;
    off += (bytes + 255) & ~(size_t)255;
    return p;
  };
  int* cnt = (int*)alloc((size_t)N_NODES * 4);
  int* rowptr = (int*)alloc((size_t)(N_NODES + 1) * 4);
  int* cursor = (int*)alloc((size_t)N_NODES * 4);
  float* dinv = (float*)alloc((size_t)N_NODES * 4);
  int* bsum = (int*)alloc((size_t)SCAN_B * 4);
  int* boff = (int*)alloc((size_t)SCAN_B * 4);
  int* eSrc = (int*)alloc((size_t)E_EDGES * 4);
  float* eW = (float*)alloc((size_t)E_EDGES * 4);
  float* h = (float*)alloc((size_t)N_NODES * 128 * 4);
  float* A = (float*)alloc((size_t)N_NODES * 128 * 4);
  ushort* wp1h = (ushort*)alloc((size_t)128 * 128 * 2);
  ushort* wp1l = (ushort*)alloc((size_t)128 * 128 * 2);
  ushort* wp2h = (ushort*)alloc((size_t)128 * 128 * 2);
  ushort* wp2l = (ushort*)alloc((size_t)128 * 128 * 2);
  ushort* wp3h = (ushort*)alloc((size_t)128 * 64 * 2);
  ushort* wp3l = (ushort*)alloc((size_t)128 * 64 * 2);

  hipMemsetAsync(cnt, 0, (size_t)N_NODES * 4, stream);
  hipMemsetAsync(cursor, 0, (size_t)N_NODES * 4, stream);

  const int EB = (E_EDGES + 255) / 256;
  const int NB = (N_NODES + 255) / 256;
  count_kernel<<<EB, 256, 0, stream>>>(dst, cnt);
  scan_part_kernel<<<SCAN_B, 256, 0, stream>>>(cnt, bsum);
  scan_tops_kernel<<<1, 128, 0, stream>>>(bsum, boff, rowptr);
  scan_write_kernel<<<SCAN_B, 256, 0, stream>>>(cnt, boff, rowptr);
  dinv_kernel<<<NB, 256, 0, stream>>>(cnt, dinv);
  scatter_kernel<<<EB, 256, 0, stream>>>(src, dst, rowptr, cursor, dinv, eSrc,
                                         eW);
  packw_kernel<128><<<8, 256, 0, stream>>>(W1, wp1h, wp1l);
  packw_kernel<128><<<8, 256, 0, stream>>>(W2, wp2h, wp2l);
  packw_kernel<64><<<4, 256, 0, stream>>>(W3, wp3h, wp3l);

  const int GB = (N_NODES + 63) / 64;  // 1563
  const int AB = (N_NODES + 3) / 4;    // 25000

  gemm_kernel<128><<<GB, 256, 0, stream>>>(x, wp1h, wp1l, h);
  agg_kernel<128><<<AB, 256, 0, stream>>>(h, rowptr, eSrc, eW, dinv, b1, A);
  gemm_kernel<128><<<GB, 256, 0, stream>>>(A, wp2h, wp2l, h);
  agg_kernel<128><<<AB, 256, 0, stream>>>(h, rowptr, eSrc, eW, dinv, b2, A);
  gemm_kernel<64><<<GB, 256, 0, stream>>>(A, wp3h, wp3l, h);
  agg_kernel<64><<<AB, 256, 0, stream>>>(h, rowptr, eSrc, eW, dinv, b3,
                                         (float*)d_out);
}

// Round 5
// 437.608 us; speedup vs baseline: 2.1118x; 1.3022x over previous
//
#include <hip/hip_runtime.h>
#include <hip/hip_bf16.h>
#include <hip/hip_fp16.h>

// GCN 3-layer forward for MI355X (gfx950).
//   1. histogram in-degree over dst          (atomicAdd int)
//   2. 3-kernel multi-block exclusive scan -> CSR rowptr (+fused dinv)
//   3. scatter edges into CSR (src, w=dinv[s]*dinv[d])
//   4. per layer: split-bf16 MFMA GEMM h=X@W (fp16 output), then
//      wave-per-node CSR gather-reduce (+bias, +self-loop, ReLU, f32 out).
// R2: agg edge loop unrolled (independent H-row gathers in flight).
// R3: scan parallelized; agg unroll 4 -> 8.
// R4: GEMM on matrix cores via split-bf16 (3 MFMAs, ~2^-17 rel err).
// R5: H stored fp16 (halves gather bytes; agg was BW-pinned at ~3.9 TB/s,
//     more MLP didn't help in R4); unroll reverted 16 -> 8 (occ 46->74%);
//     dinv fused into scan_write.

constexpr int N_NODES = 100000;
constexpr int E_EDGES = 1600000;
constexpr int SCAN_B = (N_NODES + 1023) / 1024;  // 98 blocks of 1024 elems

typedef short short8 __attribute__((ext_vector_type(8)));
typedef float f32x4 __attribute__((ext_vector_type(4)));

__global__ __launch_bounds__(256) void count_kernel(
    const int* __restrict__ dst, int* __restrict__ cnt) {
  int e = blockIdx.x * 256 + threadIdx.x;
  if (e < E_EDGES) atomicAdd(&cnt[dst[e]], 1);
}

// --- 3-kernel scan: cnt[N] -> rowptr[N+1] (exclusive), dinv fused ---
__global__ __launch_bounds__(256) void scan_part_kernel(
    const int* __restrict__ cnt, int* __restrict__ bsum) {
  __shared__ int red[256];
  const int t = threadIdx.x;
  int base = blockIdx.x * 1024 + t * 4;
  int4 v = make_int4(0, 0, 0, 0);
  if (base < N_NODES) v = *(const int4*)(cnt + base);
  red[t] = v.x + v.y + v.z + v.w;
  __syncthreads();
  for (int off = 128; off > 0; off >>= 1) {
    if (t < off) red[t] += red[t + off];
    __syncthreads();
  }
  if (t == 0) bsum[blockIdx.x] = red[0];
}

__global__ __launch_bounds__(128) void scan_tops_kernel(
    const int* __restrict__ bsum, int* __restrict__ boff,
    int* __restrict__ rowptr) {
  __shared__ int part[128];
  const int t = threadIdx.x;
  int v = (t < SCAN_B) ? bsum[t] : 0;
  part[t] = v;
  __syncthreads();
  for (int off = 1; off < 128; off <<= 1) {
    int add = (t >= off) ? part[t - off] : 0;
    __syncthreads();
    part[t] += add;
    __syncthreads();
  }
  if (t < SCAN_B) boff[t] = part[t] - v;  // exclusive
  if (t == 127) rowptr[N_NODES] = part[127];
}

__global__ __launch_bounds__(256) void scan_write_kernel(
    const int* __restrict__ cnt, const int* __restrict__ boff,
    int* __restrict__ rowptr, float* __restrict__ dinv) {
  __shared__ int part[256];
  const int t = threadIdx.x;
  int base = blockIdx.x * 1024 + t * 4;
  int4 v = make_int4(0, 0, 0, 0);
  if (base < N_NODES) v = *(const int4*)(cnt + base);
  int s = v.x + v.y + v.z + v.w;
  part[t] = s;
  __syncthreads();
  for (int off = 1; off < 256; off <<= 1) {
    int add = (t >= off) ? part[t - off] : 0;
    __syncthreads();
    part[t] += add;
    __syncthreads();
  }
  if (base < N_NODES) {
    int run = boff[blockIdx.x] + part[t] - s;
    int4 o;
    o.x = run;
    o.y = run + v.x;
    o.z = run + v.x + v.y;
    o.w = run + v.x + v.y + v.z;
    *(int4*)(rowptr + base) = o;
    float4 dv;
    dv.x = rsqrtf((float)v.x + 1.0f);  // +1 self loop
    dv.y = rsqrtf((float)v.y + 1.0f);
    dv.z = rsqrtf((float)v.z + 1.0f);
    dv.w = rsqrtf((float)v.w + 1.0f);
    *(float4*)(dinv + base) = dv;
  }
}

__global__ __launch_bounds__(256) void scatter_kernel(
    const int* __restrict__ src, const int* __restrict__ dst,
    const int* __restrict__ rowptr, int* __restrict__ cursor,
    const float* __restrict__ dinv, int* __restrict__ eSrc,
    float* __restrict__ eW) {
  int e = blockIdx.x * 256 + threadIdx.x;
  if (e < E_EDGES) {
    int s = src[e], d = dst[e];
    int pos = rowptr[d] + atomicAdd(&cursor[d], 1);
    eSrc[pos] = s;
    eW[pos] = dinv[s] * dinv[d];
  }
}

// bf16 split helpers (manual RNE; inputs finite)
__device__ inline ushort bf_round(float x) {
  uint u = __float_as_uint(x);
  return (ushort)((u + 0x7FFFu + ((u >> 16) & 1u)) >> 16);
}
__device__ inline ushort bf_split(float x, float* rem) {
  ushort h = bf_round(x);
  *rem = x - __uint_as_float((uint)h << 16);
  return h;
}

// Pack W [128][OC] f32 into fragment-linear hi/lo bf16:
// chunk id = ((nt*4 + ks)*4 + g)*16 + col holds 8 bf16:
//   W[ks*32 + g*8 + j][nt*16 + col], j = 0..7.
template <int OC>
__global__ __launch_bounds__(256) void packw_kernel(
    const float* __restrict__ W, ushort* __restrict__ hi,
    ushort* __restrict__ lo) {
  int id = blockIdx.x * 256 + threadIdx.x;
  if (id >= OC * 16) return;  // (OC/16)*4*4*16 chunks
  int col = id & 15;
  int g = (id >> 4) & 3;
  int ks = (id >> 6) & 3;
  int nt = id >> 8;
  int k0 = ks * 32 + g * 8;
  int n = nt * 16 + col;
  ushort h8[8], l8[8];
#pragma unroll
  for (int j = 0; j < 8; ++j) {
    float rem;
    h8[j] = bf_split(W[(size_t)(k0 + j) * OC + n], &rem);
    l8[j] = bf_round(rem);
  }
  size_t base = (size_t)id * 8;
#pragma unroll
  for (int j = 0; j < 8; ++j) {
    hi[base + j] = h8[j];
    lo[base + j] = l8[j];
  }
}

// Split-bf16 MFMA GEMM: H[N, OC] = X[N, 128] @ W[128, OC], H in fp16.
// 4 waves/block, 16 rows/wave (M-tile 64). W (packed hi/lo) staged in LDS;
// A-fragments loaded direct from global (X is L2/L3-resident) and split
// to hi/lo in registers. 3 MFMAs per (nt, ks): hi*hi + hi*lo + lo*hi.
template <int OC>
__global__ __launch_bounds__(256) void gemm_kernel(
    const float* __restrict__ X, const ushort* __restrict__ Whi,
    const ushort* __restrict__ Wlo, __half* __restrict__ H) {
  constexpr int NT = OC / 16;
  __shared__ ushort sWhi[OC * 128];
  __shared__ ushort sWlo[OC * 128];
  const int t = threadIdx.x;
  {  // stage packed W (contiguous, coalesced uint4 copies)
    const uint4* gh = (const uint4*)Whi;
    const uint4* gl = (const uint4*)Wlo;
    uint4* sh = (uint4*)sWhi;
    uint4* sl = (uint4*)sWlo;
    for (int i = t; i < OC * 128 / 8; i += 256) {
      sh[i] = gh[i];
      sl[i] = gl[i];
    }
  }
  const int wid = t >> 6;
  const int lane = t & 63;
  const int row = blockIdx.x * 64 + wid * 16 + (lane & 15);
  const bool ok = row < N_NODES;
  const int g = lane >> 4;  // k-group 0..3

  // Load + split A fragments for all 4 k-steps
  short8 ahi[4], alo[4];
  const float* xr = X + (size_t)row * 128;
#pragma unroll
  for (int ks = 0; ks < 4; ++ks) {
    float f[8];
    if (ok) {
      float4 f0 = *(const float4*)(xr + ks * 32 + g * 8);
      float4 f1 = *(const float4*)(xr + ks * 32 + g * 8 + 4);
      f[0] = f0.x; f[1] = f0.y; f[2] = f0.z; f[3] = f0.w;
      f[4] = f1.x; f[5] = f1.y; f[6] = f1.z; f[7] = f1.w;
    } else {
#pragma unroll
      for (int j = 0; j < 8; ++j) f[j] = 0.f;
    }
    union { short8 v; ushort u[8]; } h, l;
#pragma unroll
    for (int j = 0; j < 8; ++j) {
      float rem;
      h.u[j] = bf_split(f[j], &rem);
      l.u[j] = bf_round(rem);
    }
    ahi[ks] = h.v;
    alo[ks] = l.v;
  }
  __syncthreads();

#pragma unroll
  for (int nt = 0; nt < NT; ++nt) {
    f32x4 acc = {0.f, 0.f, 0.f, 0.f};
#pragma unroll
    for (int ks = 0; ks < 4; ++ks) {
      int off = (((nt * 4 + ks) * 4 + g) * 16 + (lane & 15)) * 8;
      short8 bhi = *(const short8*)&sWhi[off];
      short8 blo = *(const short8*)&sWlo[off];
      acc = __builtin_amdgcn_mfma_f32_16x16x32_bf16(alo[ks], bhi, acc, 0, 0, 0);
      acc = __builtin_amdgcn_mfma_f32_16x16x32_bf16(ahi[ks], blo, acc, 0, 0, 0);
      acc = __builtin_amdgcn_mfma_f32_16x16x32_bf16(ahi[ks], bhi, acc, 0, 0, 0);
    }
    // C: col = lane&15, row_in_tile = (lane>>4)*4 + r
#pragma unroll
    for (int r = 0; r < 4; ++r) {
      int rr = blockIdx.x * 64 + wid * 16 + g * 4 + r;
      if (rr < N_NODES)
        H[(size_t)rr * OC + nt * 16 + (lane & 15)] = __float2half(acc[r]);
    }
  }
}

// Wave-per-node CSR aggregation over fp16 H table:
// Y[n] = relu(b + dinv[n]^2*H[n] + sum_e w_e * H[src_e]), Y in f32.
// OC=128 -> __half2/lane (4B), OC=64 -> __half/lane (2B).
// Edge loop unrolled x8: eight independent H-row gathers in flight.
template <int OC>
__global__ __launch_bounds__(256) void agg_kernel(
    const __half* __restrict__ H, const int* __restrict__ rowptr,
    const int* __restrict__ eSrc, const float* __restrict__ eW,
    const float* __restrict__ dinv, const float* __restrict__ bias,
    float* __restrict__ Y) {
  const int wave = threadIdx.x >> 6;
  const int lane = threadIdx.x & 63;
  const int n = blockIdx.x * 4 + wave;
  if (n >= N_NODES) return;
  const float dn = dinv[n];
  const float selfw = dn * dn;
  const int beg = rowptr[n], end = rowptr[n + 1];
  const int jal = min((beg + 3) & ~3, end);      // align to 16B for int4
  const int jend = jal + ((end - jal) & ~7);     // 8-wise main loop end
  const int jend4 = jend + ((end - jend) & ~3);  // 4-wise cleanup end

  if constexpr (OC == 128) {
    const __half2* H2 = (const __half2*)H;
    float2 hv = __half22float2(H2[(size_t)n * 64 + lane]);
    float ax = hv.x * selfw, ay = hv.y * selfw;
    for (int j = beg; j < jal; ++j) {
      float w = eW[j];
      float2 v = __half22float2(H2[(size_t)eSrc[j] * 64 + lane]);
      ax = fmaf(v.x, w, ax);
      ay = fmaf(v.y, w, ay);
    }
    for (int j = jal; j < jend; j += 8) {
      int4 s0 = *(const int4*)(eSrc + j);
      int4 s1 = *(const int4*)(eSrc + j + 4);
      float4 w0 = *(const float4*)(eW + j);
      float4 w1 = *(const float4*)(eW + j + 4);
      __half2 h0 = H2[(size_t)s0.x * 64 + lane];
      __half2 h1 = H2[(size_t)s0.y * 64 + lane];
      __half2 h2 = H2[(size_t)s0.z * 64 + lane];
      __half2 h3 = H2[(size_t)s0.w * 64 + lane];
      __half2 h4 = H2[(size_t)s1.x * 64 + lane];
      __half2 h5 = H2[(size_t)s1.y * 64 + lane];
      __half2 h6 = H2[(size_t)s1.z * 64 + lane];
      __half2 h7 = H2[(size_t)s1.w * 64 + lane];
      float2 v0 = __half22float2(h0);
      float2 v1 = __half22float2(h1);
      float2 v2 = __half22float2(h2);
      float2 v3 = __half22float2(h3);
      float2 v4 = __half22float2(h4);
      float2 v5 = __half22float2(h5);
      float2 v6 = __half22float2(h6);
      float2 v7 = __half22float2(h7);
      ax = fmaf(v0.x, w0.x, ax); ay = fmaf(v0.y, w0.x, ay);
      ax = fmaf(v1.x, w0.y, ax); ay = fmaf(v1.y, w0.y, ay);
      ax = fmaf(v2.x, w0.z, ax); ay = fmaf(v2.y, w0.z, ay);
      ax = fmaf(v3.x, w0.w, ax); ay = fmaf(v3.y, w0.w, ay);
      ax = fmaf(v4.x, w1.x, ax); ay = fmaf(v4.y, w1.x, ay);
      ax = fmaf(v5.x, w1.y, ax); ay = fmaf(v5.y, w1.y, ay);
      ax = fmaf(v6.x, w1.z, ax); ay = fmaf(v6.y, w1.z, ay);
      ax = fmaf(v7.x, w1.w, ax); ay = fmaf(v7.y, w1.w, ay);
    }
    for (int j = jend; j < jend4; j += 4) {
      int4 s = *(const int4*)(eSrc + j);
      float4 w = *(const float4*)(eW + j);
      float2 v0 = __half22float2(H2[(size_t)s.x * 64 + lane]);
      float2 v1 = __half22float2(H2[(size_t)s.y * 64 + lane]);
      float2 v2 = __half22float2(H2[(size_t)s.z * 64 + lane]);
      float2 v3 = __half22float2(H2[(size_t)s.w * 64 + lane]);
      ax = fmaf(v0.x, w.x, ax); ay = fmaf(v0.y, w.x, ay);
      ax = fmaf(v1.x, w.y, ax); ay = fmaf(v1.y, w.y, ay);
      ax = fmaf(v2.x, w.z, ax); ay = fmaf(v2.y, w.z, ay);
      ax = fmaf(v3.x, w.w, ax); ay = fmaf(v3.y, w.w, ay);
    }
    for (int j = jend4; j < end; ++j) {
      float w = eW[j];
      float2 v = __half22float2(H2[(size_t)eSrc[j] * 64 + lane]);
      ax = fmaf(v.x, w, ax);
      ay = fmaf(v.y, w, ay);
    }
    float2 bb = ((const float2*)bias)[lane];
    float2 o;
    o.x = fmaxf(ax + bb.x, 0.f);
    o.y = fmaxf(ay + bb.y, 0.f);
    ((float2*)Y)[(size_t)n * 64 + lane] = o;
  } else {
    float a = __half2float(H[(size_t)n * 64 + lane]) * selfw;
    for (int j = beg; j < jal; ++j)
      a = fmaf(__half2float(H[(size_t)eSrc[j] * 64 + lane]), eW[j], a);
    for (int j = jal; j < jend; j += 8) {
      int4 s0 = *(const int4*)(eSrc + j);
      int4 s1 = *(const int4*)(eSrc + j + 4);
      float4 w0 = *(const float4*)(eW + j);
      float4 w1 = *(const float4*)(eW + j + 4);
      __half h0 = H[(size_t)s0.x * 64 + lane];
      __half h1 = H[(size_t)s0.y * 64 + lane];
      __half h2 = H[(size_t)s0.z * 64 + lane];
      __half h3 = H[(size_t)s0.w * 64 + lane];
      __half h4 = H[(size_t)s1.x * 64 + lane];
      __half h5 = H[(size_t)s1.y * 64 + lane];
      __half h6 = H[(size_t)s1.z * 64 + lane];
      __half h7 = H[(size_t)s1.w * 64 + lane];
      a = fmaf(__half2float(h0), w0.x, a);
      a = fmaf(__half2float(h1), w0.y, a);
      a = fmaf(__half2float(h2), w0.z, a);
      a = fmaf(__half2float(h3), w0.w, a);
      a = fmaf(__half2float(h4), w1.x, a);
      a = fmaf(__half2float(h5), w1.y, a);
      a = fmaf(__half2float(h6), w1.z, a);
      a = fmaf(__half2float(h7), w1.w, a);
    }
    for (int j = jend; j < jend4; j += 4) {
      int4 s = *(const int4*)(eSrc + j);
      float4 w = *(const float4*)(eW + j);
      a = fmaf(__half2float(H[(size_t)s.x * 64 + lane]), w.x, a);
      a = fmaf(__half2float(H[(size_t)s.y * 64 + lane]), w.y, a);
      a = fmaf(__half2float(H[(size_t)s.z * 64 + lane]), w.z, a);
      a = fmaf(__half2float(H[(size_t)s.w * 64 + lane]), w.w, a);
    }
    for (int j = jend4; j < end; ++j)
      a = fmaf(__half2float(H[(size_t)eSrc[j] * 64 + lane]), eW[j], a);
    Y[(size_t)n * 64 + lane] = fmaxf(a + bias[lane], 0.f);
  }
}

extern "C" void kernel_launch(void* const* d_in, const int* in_sizes, int n_in,
                              void* d_out, int out_size, void* d_ws,
                              size_t ws_size, hipStream_t stream) {
  const float* x = (const float*)d_in[0];
  const int* ei = (const int*)d_in[1];
  const float* W1 = (const float*)d_in[2];
  const float* b1 = (const float*)d_in[3];
  const float* W2 = (const float*)d_in[4];
  const float* b2 = (const float*)d_in[5];
  const float* W3 = (const float*)d_in[6];
  const float* b3 = (const float*)d_in[7];
  const int* src = ei;
  const int* dst = ei + E_EDGES;

  size_t off = 0;
  auto alloc = [&](size_t bytes) -> void* {
    void* p = (char*)d_ws + off;
    off += (bytes + 255) & ~(size_t)255;
    return p;
  };
  int* cnt = (int*)alloc((size_t)N_NODES * 4);
  int* rowptr = (int*)alloc((size_t)(N_NODES + 1) * 4);
  int* cursor = (int*)alloc((size_t)N_NODES * 4);
  float* dinv = (float*)alloc((size_t)N_NODES * 4);
  int* bsum = (int*)alloc((size_t)SCAN_B * 4);
  int* boff = (int*)alloc((size_t)SCAN_B * 4);
  int* eSrc = (int*)alloc((size_t)E_EDGES * 4);
  float* eW = (float*)alloc((size_t)E_EDGES * 4);
  __half* h = (__half*)alloc((size_t)N_NODES * 128 * 2);
  float* A = (float*)alloc((size_t)N_NODES * 128 * 4);
  ushort* wp1h = (ushort*)alloc((size_t)128 * 128 * 2);
  ushort* wp1l = (ushort*)alloc((size_t)128 * 128 * 2);
  ushort* wp2h = (ushort*)alloc((size_t)128 * 128 * 2);
  ushort* wp2l = (ushort*)alloc((size_t)128 * 128 * 2);
  ushort* wp3h = (ushort*)alloc((size_t)128 * 64 * 2);
  ushort* wp3l = (ushort*)alloc((size_t)128 * 64 * 2);

  hipMemsetAsync(cnt, 0, (size_t)N_NODES * 4, stream);
  hipMemsetAsync(cursor, 0, (size_t)N_NODES * 4, stream);

  const int EB = (E_EDGES + 255) / 256;
  count_kernel<<<EB, 256, 0, stream>>>(dst, cnt);
  scan_part_kernel<<<SCAN_B, 256, 0, stream>>>(cnt, bsum);
  scan_tops_kernel<<<1, 128, 0, stream>>>(bsum, boff, rowptr);
  scan_write_kernel<<<SCAN_B, 256, 0, stream>>>(cnt, boff, rowptr, dinv);
  scatter_kernel<<<EB, 256, 0, stream>>>(src, dst, rowptr, cursor, dinv, eSrc,
                                         eW);
  packw_kernel<128><<<8, 256, 0, stream>>>(W1, wp1h, wp1l);
  packw_kernel<128><<<8, 256, 0, stream>>>(W2, wp2h, wp2l);
  packw_kernel<64><<<4, 256, 0, stream>>>(W3, wp3h, wp3l);

  const int GB = (N_NODES + 63) / 64;  // 1563
  const int AB = (N_NODES + 3) / 4;    // 25000

  gemm_kernel<128><<<GB, 256, 0, stream>>>(x, wp1h, wp1l, h);
  agg_kernel<128><<<AB, 256, 0, stream>>>(h, rowptr, eSrc, eW, dinv, b1, A);
  gemm_kernel<128><<<GB, 256, 0, stream>>>(A, wp2h, wp2l, h);
  agg_kernel<128><<<AB, 256, 0, stream>>>(h, rowptr, eSrc, eW, dinv, b2, A);
  gemm_kernel<64><<<GB, 256, 0, stream>>>(A, wp3h, wp3l, h);
  agg_kernel<64><<<AB, 256, 0, stream>>>(h, rowptr, eSrc, eW, dinv, b3,
                                         (float*)d_out);
}

// Round 6
// 426.659 us; speedup vs baseline: 2.1660x; 1.0257x over previous
//
#include <hip/hip_runtime.h>
#include <hip/hip_bf16.h>
#include <hip/hip_fp16.h>

// GCN 3-layer forward for MI355X (gfx950).
//   1. histogram in-degree over dst          (atomicAdd int)
//   2. 3-kernel multi-block exclusive scan -> CSR rowptr (+fused dinv)
//   3. XCD-grouped scatter edges into packed CSR (src, w) int2
//   4. per layer: split-bf16 MFMA GEMM h=X@W (fp16 output), then
//      wave-per-node CSR gather-reduce (+bias, +self-loop, ReLU, f32 out).
// R2: agg edge loop unrolled (independent H-row gathers in flight).
// R3: scan parallelized; agg unroll 4 -> 8.
// R4: GEMM on matrix cores via split-bf16 (3 MFMAs, ~2^-17 rel err).
// R5: H stored fp16 (agg was BW-pinned); unroll back to 8; dinv fused.
// R6: scatter was 12x write-amplified (155 MB for 12.8 MB logical: random
//     partial-line stores from all 8 XCDs). Fix: pack (src,w) int2 (one
//     store/edge) + XCD-range grouping (blockIdx%8 owns dst-range slice,
//     writes stay in one XCD's L2 and merge).

constexpr int N_NODES = 100000;
constexpr int E_EDGES = 1600000;
constexpr int SCAN_B = (N_NODES + 1023) / 1024;  // 98 blocks of 1024 elems
constexpr int XGROUPS = 8;
constexpr int XRANGE = (N_NODES + XGROUPS - 1) / XGROUPS;  // 12500

typedef short short8 __attribute__((ext_vector_type(8)));
typedef float f32x4 __attribute__((ext_vector_type(4)));

__global__ __launch_bounds__(256) void count_kernel(
    const int* __restrict__ dst, int* __restrict__ cnt) {
  int e = blockIdx.x * 256 + threadIdx.x;
  if (e < E_EDGES) atomicAdd(&cnt[dst[e]], 1);
}

// --- 3-kernel scan: cnt[N] -> rowptr[N+1] (exclusive), dinv fused ---
__global__ __launch_bounds__(256) void scan_part_kernel(
    const int* __restrict__ cnt, int* __restrict__ bsum) {
  __shared__ int red[256];
  const int t = threadIdx.x;
  int base = blockIdx.x * 1024 + t * 4;
  int4 v = make_int4(0, 0, 0, 0);
  if (base < N_NODES) v = *(const int4*)(cnt + base);
  red[t] = v.x + v.y + v.z + v.w;
  __syncthreads();
  for (int off = 128; off > 0; off >>= 1) {
    if (t < off) red[t] += red[t + off];
    __syncthreads();
  }
  if (t == 0) bsum[blockIdx.x] = red[0];
}

__global__ __launch_bounds__(128) void scan_tops_kernel(
    const int* __restrict__ bsum, int* __restrict__ boff,
    int* __restrict__ rowptr) {
  __shared__ int part[128];
  const int t = threadIdx.x;
  int v = (t < SCAN_B) ? bsum[t] : 0;
  part[t] = v;
  __syncthreads();
  for (int off = 1; off < 128; off <<= 1) {
    int add = (t >= off) ? part[t - off] : 0;
    __syncthreads();
    part[t] += add;
    __syncthreads();
  }
  if (t < SCAN_B) boff[t] = part[t] - v;  // exclusive
  if (t == 127) rowptr[N_NODES] = part[127];
}

__global__ __launch_bounds__(256) void scan_write_kernel(
    const int* __restrict__ cnt, const int* __restrict__ boff,
    int* __restrict__ rowptr, float* __restrict__ dinv) {
  __shared__ int part[256];
  const int t = threadIdx.x;
  int base = blockIdx.x * 1024 + t * 4;
  int4 v = make_int4(0, 0, 0, 0);
  if (base < N_NODES) v = *(const int4*)(cnt + base);
  int s = v.x + v.y + v.z + v.w;
  part[t] = s;
  __syncthreads();
  for (int off = 1; off < 256; off <<= 1) {
    int add = (t >= off) ? part[t - off] : 0;
    __syncthreads();
    part[t] += add;
    __syncthreads();
  }
  if (base < N_NODES) {
    int run = boff[blockIdx.x] + part[t] - s;
    int4 o;
    o.x = run;
    o.y = run + v.x;
    o.z = run + v.x + v.y;
    o.w = run + v.x + v.y + v.z;
    *(int4*)(rowptr + base) = o;
    float4 dv;
    dv.x = rsqrtf((float)v.x + 1.0f);  // +1 self loop
    dv.y = rsqrtf((float)v.y + 1.0f);
    dv.z = rsqrtf((float)v.z + 1.0f);
    dv.w = rsqrtf((float)v.w + 1.0f);
    *(float4*)(dinv + base) = dv;
  }
}

// XCD-grouped scatter: blocks with blockIdx%8==g (round-robin -> XCD g)
// handle edges whose dst is in [g*XRANGE, (g+1)*XRANGE). Each group's
// stores land in a 1.6 MB slice of eSW -> lines stay in one XCD's L2
// and merge. One packed int2 (src, w-bits) store per edge.
__global__ __launch_bounds__(256) void scatter_kernel(
    const int* __restrict__ src, const int* __restrict__ dst,
    const int* __restrict__ rowptr, int* __restrict__ cursor,
    const float* __restrict__ dinv, int2* __restrict__ eSW) {
  const int g = blockIdx.x & 7;
  const int blk = blockIdx.x >> 3;
  const int nblk = gridDim.x >> 3;
  const int lo = g * XRANGE;
  const int hi = min(lo + XRANGE, N_NODES);
  for (int e = blk * 256 + threadIdx.x; e < E_EDGES; e += nblk * 256) {
    int d = dst[e];
    if (d >= lo && d < hi) {
      int s = src[e];
      int pos = rowptr[d] + atomicAdd(&cursor[d], 1);
      eSW[pos] = make_int2(s, __float_as_int(dinv[s] * dinv[d]));
    }
  }
}

// bf16 split helpers (manual RNE; inputs finite)
__device__ inline ushort bf_round(float x) {
  uint u = __float_as_uint(x);
  return (ushort)((u + 0x7FFFu + ((u >> 16) & 1u)) >> 16);
}
__device__ inline ushort bf_split(float x, float* rem) {
  ushort h = bf_round(x);
  *rem = x - __uint_as_float((uint)h << 16);
  return h;
}

// Pack W [128][OC] f32 into fragment-linear hi/lo bf16:
// chunk id = ((nt*4 + ks)*4 + g)*16 + col holds 8 bf16:
//   W[ks*32 + g*8 + j][nt*16 + col], j = 0..7.
template <int OC>
__global__ __launch_bounds__(256) void packw_kernel(
    const float* __restrict__ W, ushort* __restrict__ hi,
    ushort* __restrict__ lo) {
  int id = blockIdx.x * 256 + threadIdx.x;
  if (id >= OC * 16) return;  // (OC/16)*4*4*16 chunks
  int col = id & 15;
  int g = (id >> 4) & 3;
  int ks = (id >> 6) & 3;
  int nt = id >> 8;
  int k0 = ks * 32 + g * 8;
  int n = nt * 16 + col;
  ushort h8[8], l8[8];
#pragma unroll
  for (int j = 0; j < 8; ++j) {
    float rem;
    h8[j] = bf_split(W[(size_t)(k0 + j) * OC + n], &rem);
    l8[j] = bf_round(rem);
  }
  size_t base = (size_t)id * 8;
#pragma unroll
  for (int j = 0; j < 8; ++j) {
    hi[base + j] = h8[j];
    lo[base + j] = l8[j];
  }
}

// Split-bf16 MFMA GEMM: H[N, OC] = X[N, 128] @ W[128, OC], H in fp16.
// 4 waves/block, 16 rows/wave (M-tile 64). W (packed hi/lo) staged in LDS;
// A-fragments loaded direct from global (X is L2/L3-resident) and split
// to hi/lo in registers. 3 MFMAs per (nt, ks): hi*hi + hi*lo + lo*hi.
template <int OC>
__global__ __launch_bounds__(256) void gemm_kernel(
    const float* __restrict__ X, const ushort* __restrict__ Whi,
    const ushort* __restrict__ Wlo, __half* __restrict__ H) {
  constexpr int NT = OC / 16;
  __shared__ ushort sWhi[OC * 128];
  __shared__ ushort sWlo[OC * 128];
  const int t = threadIdx.x;
  {  // stage packed W (contiguous, coalesced uint4 copies)
    const uint4* gh = (const uint4*)Whi;
    const uint4* gl = (const uint4*)Wlo;
    uint4* sh = (uint4*)sWhi;
    uint4* sl = (uint4*)sWlo;
    for (int i = t; i < OC * 128 / 8; i += 256) {
      sh[i] = gh[i];
      sl[i] = gl[i];
    }
  }
  const int wid = t >> 6;
  const int lane = t & 63;
  const int row = blockIdx.x * 64 + wid * 16 + (lane & 15);
  const bool ok = row < N_NODES;
  const int g = lane >> 4;  // k-group 0..3

  // Load + split A fragments for all 4 k-steps
  short8 ahi[4], alo[4];
  const float* xr = X + (size_t)row * 128;
#pragma unroll
  for (int ks = 0; ks < 4; ++ks) {
    float f[8];
    if (ok) {
      float4 f0 = *(const float4*)(xr + ks * 32 + g * 8);
      float4 f1 = *(const float4*)(xr + ks * 32 + g * 8 + 4);
      f[0] = f0.x; f[1] = f0.y; f[2] = f0.z; f[3] = f0.w;
      f[4] = f1.x; f[5] = f1.y; f[6] = f1.z; f[7] = f1.w;
    } else {
#pragma unroll
      for (int j = 0; j < 8; ++j) f[j] = 0.f;
    }
    union { short8 v; ushort u[8]; } h, l;
#pragma unroll
    for (int j = 0; j < 8; ++j) {
      float rem;
      h.u[j] = bf_split(f[j], &rem);
      l.u[j] = bf_round(rem);
    }
    ahi[ks] = h.v;
    alo[ks] = l.v;
  }
  __syncthreads();

#pragma unroll
  for (int nt = 0; nt < NT; ++nt) {
    f32x4 acc = {0.f, 0.f, 0.f, 0.f};
#pragma unroll
    for (int ks = 0; ks < 4; ++ks) {
      int off = (((nt * 4 + ks) * 4 + g) * 16 + (lane & 15)) * 8;
      short8 bhi = *(const short8*)&sWhi[off];
      short8 blo = *(const short8*)&sWlo[off];
      acc = __builtin_amdgcn_mfma_f32_16x16x32_bf16(alo[ks], bhi, acc, 0, 0, 0);
      acc = __builtin_amdgcn_mfma_f32_16x16x32_bf16(ahi[ks], blo, acc, 0, 0, 0);
      acc = __builtin_amdgcn_mfma_f32_16x16x32_bf16(ahi[ks], bhi, acc, 0, 0, 0);
    }
    // C: col = lane&15, row_in_tile = (lane>>4)*4 + r
#pragma unroll
    for (int r = 0; r < 4; ++r) {
      int rr = blockIdx.x * 64 + wid * 16 + g * 4 + r;
      if (rr < N_NODES)
        H[(size_t)rr * OC + nt * 16 + (lane & 15)] = __float2half(acc[r]);
    }
  }
}

// Wave-per-node CSR aggregation over fp16 H table, packed (src,w) edges:
// Y[n] = relu(b + dinv[n]^2*H[n] + sum_e w_e * H[src_e]), Y in f32.
// Edge loop unrolled x8 (int4 loads of 2 packed edges each): eight
// independent H-row gathers in flight per wave.
template <int OC>
__global__ __launch_bounds__(256) void agg_kernel(
    const __half* __restrict__ H, const int* __restrict__ rowptr,
    const int2* __restrict__ eSW, const float* __restrict__ dinv,
    const float* __restrict__ bias, float* __restrict__ Y) {
  const int wave = threadIdx.x >> 6;
  const int lane = threadIdx.x & 63;
  const int n = blockIdx.x * 4 + wave;
  if (n >= N_NODES) return;
  const float dn = dinv[n];
  const float selfw = dn * dn;
  const int beg = rowptr[n], end = rowptr[n + 1];
  const int jal = min(beg + (beg & 1), end);     // align to 16B (even idx)
  const int jend = jal + ((end - jal) & ~7);     // 8-wise main loop end
  const int jend2 = jend + ((end - jend) & ~1);  // 2-wise cleanup end

  if constexpr (OC == 128) {
    const __half2* H2 = (const __half2*)H;
    float2 hv = __half22float2(H2[(size_t)n * 64 + lane]);
    float ax = hv.x * selfw, ay = hv.y * selfw;
    for (int j = beg; j < jal; ++j) {
      int2 p = eSW[j];
      float2 v = __half22float2(H2[(size_t)p.x * 64 + lane]);
      float w = __int_as_float(p.y);
      ax = fmaf(v.x, w, ax);
      ay = fmaf(v.y, w, ay);
    }
    for (int j = jal; j < jend; j += 8) {
      int4 p0 = *(const int4*)(eSW + j);      // s0 w0 s1 w1
      int4 p1 = *(const int4*)(eSW + j + 2);
      int4 p2 = *(const int4*)(eSW + j + 4);
      int4 p3 = *(const int4*)(eSW + j + 6);
      __half2 h0 = H2[(size_t)p0.x * 64 + lane];
      __half2 h1 = H2[(size_t)p0.z * 64 + lane];
      __half2 h2 = H2[(size_t)p1.x * 64 + lane];
      __half2 h3 = H2[(size_t)p1.z * 64 + lane];
      __half2 h4 = H2[(size_t)p2.x * 64 + lane];
      __half2 h5 = H2[(size_t)p2.z * 64 + lane];
      __half2 h6 = H2[(size_t)p3.x * 64 + lane];
      __half2 h7 = H2[(size_t)p3.z * 64 + lane];
      float2 v0 = __half22float2(h0);
      float2 v1 = __half22float2(h1);
      float2 v2 = __half22float2(h2);
      float2 v3 = __half22float2(h3);
      float2 v4 = __half22float2(h4);
      float2 v5 = __half22float2(h5);
      float2 v6 = __half22float2(h6);
      float2 v7 = __half22float2(h7);
      ax = fmaf(v0.x, __int_as_float(p0.y), ax);
      ay = fmaf(v0.y, __int_as_float(p0.y), ay);
      ax = fmaf(v1.x, __int_as_float(p0.w), ax);
      ay = fmaf(v1.y, __int_as_float(p0.w), ay);
      ax = fmaf(v2.x, __int_as_float(p1.y), ax);
      ay = fmaf(v2.y, __int_as_float(p1.y), ay);
      ax = fmaf(v3.x, __int_as_float(p1.w), ax);
      ay = fmaf(v3.y, __int_as_float(p1.w), ay);
      ax = fmaf(v4.x, __int_as_float(p2.y), ax);
      ay = fmaf(v4.y, __int_as_float(p2.y), ay);
      ax = fmaf(v5.x, __int_as_float(p2.w), ax);
      ay = fmaf(v5.y, __int_as_float(p2.w), ay);
      ax = fmaf(v6.x, __int_as_float(p3.y), ax);
      ay = fmaf(v6.y, __int_as_float(p3.y), ay);
      ax = fmaf(v7.x, __int_as_float(p3.w), ax);
      ay = fmaf(v7.y, __int_as_float(p3.w), ay);
    }
    for (int j = jend; j < jend2; j += 2) {
      int4 p = *(const int4*)(eSW + j);
      float2 v0 = __half22float2(H2[(size_t)p.x * 64 + lane]);
      float2 v1 = __half22float2(H2[(size_t)p.z * 64 + lane]);
      ax = fmaf(v0.x, __int_as_float(p.y), ax);
      ay = fmaf(v0.y, __int_as_float(p.y), ay);
      ax = fmaf(v1.x, __int_as_float(p.w), ax);
      ay = fmaf(v1.y, __int_as_float(p.w), ay);
    }
    for (int j = jend2; j < end; ++j) {
      int2 p = eSW[j];
      float2 v = __half22float2(H2[(size_t)p.x * 64 + lane]);
      float w = __int_as_float(p.y);
      ax = fmaf(v.x, w, ax);
      ay = fmaf(v.y, w, ay);
    }
    float2 bb = ((const float2*)bias)[lane];
    float2 o;
    o.x = fmaxf(ax + bb.x, 0.f);
    o.y = fmaxf(ay + bb.y, 0.f);
    ((float2*)Y)[(size_t)n * 64 + lane] = o;
  } else {
    float a = __half2float(H[(size_t)n * 64 + lane]) * selfw;
    for (int j = beg; j < jal; ++j) {
      int2 p = eSW[j];
      a = fmaf(__half2float(H[(size_t)p.x * 64 + lane]),
               __int_as_float(p.y), a);
    }
    for (int j = jal; j < jend; j += 8) {
      int4 p0 = *(const int4*)(eSW + j);
      int4 p1 = *(const int4*)(eSW + j + 2);
      int4 p2 = *(const int4*)(eSW + j + 4);
      int4 p3 = *(const int4*)(eSW + j + 6);
      __half h0 = H[(size_t)p0.x * 64 + lane];
      __half h1 = H[(size_t)p0.z * 64 + lane];
      __half h2 = H[(size_t)p1.x * 64 + lane];
      __half h3 = H[(size_t)p1.z * 64 + lane];
      __half h4 = H[(size_t)p2.x * 64 + lane];
      __half h5 = H[(size_t)p2.z * 64 + lane];
      __half h6 = H[(size_t)p3.x * 64 + lane];
      __half h7 = H[(size_t)p3.z * 64 + lane];
      a = fmaf(__half2float(h0), __int_as_float(p0.y), a);
      a = fmaf(__half2float(h1), __int_as_float(p0.w), a);
      a = fmaf(__half2float(h2), __int_as_float(p1.y), a);
      a = fmaf(__half2float(h3), __int_as_float(p1.w), a);
      a = fmaf(__half2float(h4), __int_as_float(p2.y), a);
      a = fmaf(__half2float(h5), __int_as_float(p2.w), a);
      a = fmaf(__half2float(h6), __int_as_float(p3.y), a);
      a = fmaf(__half2float(h7), __int_as_float(p3.w), a);
    }
    for (int j = jend; j < jend2; j += 2) {
      int4 p = *(const int4*)(eSW + j);
      a = fmaf(__half2float(H[(size_t)p.x * 64 + lane]),
               __int_as_float(p.y), a);
      a = fmaf(__half2float(H[(size_t)p.z * 64 + lane]),
               __int_as_float(p.w), a);
    }
    for (int j = jend2; j < end; ++j) {
      int2 p = eSW[j];
      a = fmaf(__half2float(H[(size_t)p.x * 64 + lane]),
               __int_as_float(p.y), a);
    }
    Y[(size_t)n * 64 + lane] = fmaxf(a + bias[lane], 0.f);
  }
}

extern "C" void kernel_launch(void* const* d_in, const int* in_sizes, int n_in,
                              void* d_out, int out_size, void* d_ws,
                              size_t ws_size, hipStream_t stream) {
  const float* x = (const float*)d_in[0];
  const int* ei = (const int*)d_in[1];
  const float* W1 = (const float*)d_in[2];
  const float* b1 = (const float*)d_in[3];
  const float* W2 = (const float*)d_in[4];
  const float* b2 = (const float*)d_in[5];
  const float* W3 = (const float*)d_in[6];
  const float* b3 = (const float*)d_in[7];
  const int* src = ei;
  const int* dst = ei + E_EDGES;

  size_t off = 0;
  auto alloc = [&](size_t bytes) -> void* {
    void* p = (char*)d_ws + off;
    off += (bytes + 255) & ~(size_t)255;
    return p;
  };
  int* cnt = (int*)alloc((size_t)N_NODES * 4);
  int* rowptr = (int*)alloc((size_t)(N_NODES + 1) * 4);
  int* cursor = (int*)alloc((size_t)N_NODES * 4);
  float* dinv = (float*)alloc((size_t)N_NODES * 4);
  int* bsum = (int*)alloc((size_t)SCAN_B * 4);
  int* boff = (int*)alloc((size_t)SCAN_B * 4);
  int2* eSW = (int2*)alloc((size_t)E_EDGES * 8);
  __half* h = (__half*)alloc((size_t)N_NODES * 128 * 2);
  float* A = (float*)alloc((size_t)N_NODES * 128 * 4);
  ushort* wp1h = (ushort*)alloc((size_t)128 * 128 * 2);
  ushort* wp1l = (ushort*)alloc((size_t)128 * 128 * 2);
  ushort* wp2h = (ushort*)alloc((size_t)128 * 128 * 2);
  ushort* wp2l = (ushort*)alloc((size_t)128 * 128 * 2);
  ushort* wp3h = (ushort*)alloc((size_t)128 * 64 * 2);
  ushort* wp3l = (ushort*)alloc((size_t)128 * 64 * 2);

  hipMemsetAsync(cnt, 0, (size_t)N_NODES * 4, stream);
  hipMemsetAsync(cursor, 0, (size_t)N_NODES * 4, stream);

  const int EB = (E_EDGES + 255) / 256;
  count_kernel<<<EB, 256, 0, stream>>>(dst, cnt);
  scan_part_kernel<<<SCAN_B, 256, 0, stream>>>(cnt, bsum);
  scan_tops_kernel<<<1, 128, 0, stream>>>(bsum, boff, rowptr);
  scan_write_kernel<<<SCAN_B, 256, 0, stream>>>(cnt, boff, rowptr, dinv);
  scatter_kernel<<<2048, 256, 0, stream>>>(src, dst, rowptr, cursor, dinv,
                                           eSW);
  packw_kernel<128><<<8, 256, 0, stream>>>(W1, wp1h, wp1l);
  packw_kernel<128><<<8, 256, 0, stream>>>(W2, wp2h, wp2l);
  packw_kernel<64><<<4, 256, 0, stream>>>(W3, wp3h, wp3l);

  const int GB = (N_NODES + 63) / 64;  // 1563
  const int AB = (N_NODES + 3) / 4;    // 25000

  gemm_kernel<128><<<GB, 256, 0, stream>>>(x, wp1h, wp1l, h);
  agg_kernel<128><<<AB, 256, 0, stream>>>(h, rowptr, eSW, dinv, b1, A);
  gemm_kernel<128><<<GB, 256, 0, stream>>>(A, wp2h, wp2l, h);
  agg_kernel<128><<<AB, 256, 0, stream>>>(h, rowptr, eSW, dinv, b2, A);
  gemm_kernel<64><<<GB, 256, 0, stream>>>(A, wp3h, wp3l, h);
  agg_kernel<64><<<AB, 256, 0, stream>>>(h, rowptr, eSW, dinv, b3,
                                         (float*)d_out);
}